// Round 1
// 629.336 us; speedup vs baseline: 1.0604x; 1.0604x over previous
//
#include <hip/hip_runtime.h>
#include <math.h>

#define N_VARS 40000
#define FEAT 128
#define N_EDGES 200000
#define N_MSG (2*N_EDGES)
#define N_CONFP 100000
#define T_ITERS 3
#define EPSF 1e-5f

#define NB_CONF 782              // ceil(200000/256)
#define NB_LOSS 3517             // ceil(900000/256)
#define NB_STAT 157              // ceil(40000/256)
#define OUT_TOTAL 1120003
#define NCONF_SLOT 1120002       // sequential carve: 1+1+480000+600000+40000

typedef short short8 __attribute__((ext_vector_type(8)));
typedef float floatx4 __attribute__((ext_vector_type(4)));
typedef unsigned short ushort4v __attribute__((ext_vector_type(4)));

__device__ __forceinline__ float scrub0(float x){
  unsigned u = __float_as_uint(x);
  return ((u & 0x7F800000u) == 0x7F800000u) ? 0.f : x;
}
__device__ __forceinline__ unsigned short f2bf_rne(float x){
  unsigned u = __float_as_uint(x);
  u += 0x7FFFu + ((u >> 16) & 1u);
  return (unsigned short)(u >> 16);
}
__device__ __forceinline__ float bf2f(unsigned short h){
  return __uint_as_float(((unsigned)h) << 16);
}

__global__ __launch_bounds__(256) void k_zero_agg(float4* __restrict__ p){
  p[blockIdx.x*256 + threadIdx.x] = make_float4(0.f,0.f,0.f,0.f);
}
__global__ __launch_bounds__(256) void k_zero_int(int* __restrict__ p, int n){
  int i = blockIdx.x*256 + threadIdx.x;
  if (i < n) p[i] = 0;
}

// ---- CSR build over message ids m in [0,2E): target = m<E ? idxL[m] : idxR[m-E]
__global__ __launch_bounds__(256) void k_hist(const int* __restrict__ idxL,
    const int* __restrict__ idxR, int* __restrict__ cnt){
  int m = blockIdx.x*256 + threadIdx.x;
  if (m < N_MSG){
    int t = (m < N_EDGES) ? idxL[m] : idxR[m - N_EDGES];
    atomicAdd(&cnt[t], 1);
  }
}
__global__ __launch_bounds__(256) void k_scan1(const int* __restrict__ cnt,
    int* __restrict__ pos, int* __restrict__ blk_tot){
  const int tid = threadIdx.x;
  const int idx = blockIdx.x*256 + tid;
  int v = (idx < N_VARS) ? cnt[idx] : 0;
  __shared__ int sh[256];
  sh[tid] = v;
  __syncthreads();
#pragma unroll
  for (int o = 1; o < 256; o <<= 1){
    int add = (tid >= o) ? sh[tid - o] : 0;
    __syncthreads();
    sh[tid] += add;
    __syncthreads();
  }
  if (idx < N_VARS) pos[idx] = sh[tid] - v;
  if (tid == 255) blk_tot[blockIdx.x] = sh[255];
}
__global__ __launch_bounds__(256) void k_scan2(const int* __restrict__ blk_tot,
    int* __restrict__ blk_off){
  const int tid = threadIdx.x;
  int v = (tid < NB_STAT) ? blk_tot[tid] : 0;
  __shared__ int sh[256];
  sh[tid] = v;
  __syncthreads();
#pragma unroll
  for (int o = 1; o < 256; o <<= 1){
    int add = (tid >= o) ? sh[tid - o] : 0;
    __syncthreads();
    sh[tid] += add;
    __syncthreads();
  }
  if (tid < NB_STAT) blk_off[tid] = sh[tid] - v;
}
__global__ __launch_bounds__(256) void k_scan3(int* __restrict__ pos,
    const int* __restrict__ blk_off){
  const int idx = blockIdx.x*256 + threadIdx.x;
  if (idx < N_VARS) pos[idx] += blk_off[blockIdx.x];
}
// fill: writes INVERSE permutation morder[slot]=m and nodeof[slot]=target
__global__ __launch_bounds__(256) void k_fill(const int* __restrict__ idxL,
    const int* __restrict__ idxR, int* __restrict__ pos,
    int* __restrict__ morder, int* __restrict__ nodeof){
  int m = blockIdx.x*256 + threadIdx.x;
  if (m < N_MSG){
    int t = (m < N_EDGES) ? idxL[m] : idxR[m - N_EDGES];
    int slot = atomicAdd(&pos[t], 1);
    morder[slot] = m;
    nodeof[slot] = t;
  }
}

// ---- pack W2 (128x128 f32) into B-fragment-ordered bf16 (8 ntiles) ----
__global__ __launch_bounds__(256) void k_prep(const float* __restrict__ W2,
                                              unsigned short* __restrict__ W2pack){
  int gid = blockIdx.x*256 + threadIdx.x;
  int lane = gid & 63;
  int ks = (gid >> 6) & 3;
  int ntg = gid >> 8;
  int kbase = ks*32 + (lane >> 4)*8;
  int n = ntg*16 + (lane & 15);
#pragma unroll
  for (int j = 0; j < 8; ++j)
    W2pack[gid*8 + j] = f2bf_rne(W2[(kbase + j)*FEAT + n]);
}
__global__ __launch_bounds__(256) void k_prep_w1(const float* __restrict__ W1,
                                                 unsigned short* __restrict__ W1pack){
  int gid = blockIdx.x*256 + threadIdx.x;
  int lane = gid & 63;
  int ks = (gid >> 6) & 3;
  int ntg = gid >> 8;
  int kbase = ks*32 + (lane >> 4)*8;
  int n = ntg*16 + (lane & 15);
#pragma unroll
  for (int j = 0; j < 8; ++j){
    int k = kbase + j;
    float v = (n < 128) ? W1[k*FEAT + n] : W1[(128 + k)*FEAT + (n - 128)];
    W1pack[gid*8 + j] = f2bf_rne(v);
  }
}

// ---- PQ = x @ [W1top | W1bot] via MFMA bf16 -> bf16 store; also zeroes red ----
#define X_STRIDE 136
__global__ __launch_bounds__(256) void k_pq(const float* __restrict__ xf,
                                            const unsigned short* __restrict__ xb,
                                            int src_f32,
                                            const unsigned short* __restrict__ W1pack,
                                            unsigned short* __restrict__ PQb,
                                            float* __restrict__ red){
  __shared__ __align__(16) unsigned short Xbf[32*X_STRIDE];
  const int tid = threadIdx.x;
  const int row0 = blockIdx.x * 32;
  if (blockIdx.x == 0) red[tid] = 0.f;
  if (src_f32){
    const int c4 = (tid & 31)*4, g8 = tid >> 5;
#pragma unroll
    for (int r = 0; r < 4; ++r){
      int row = g8*4 + r;
      const float4 v = *(const float4*)&xf[(row0 + row)*FEAT + c4];
      ushort4v u;
      u.x = f2bf_rne(v.x); u.y = f2bf_rne(v.y);
      u.z = f2bf_rne(v.z); u.w = f2bf_rne(v.w);
      *(ushort4v*)&Xbf[row*X_STRIDE + c4] = u;
    }
  } else {
    const int c8 = (tid & 15)*8, g16 = tid >> 4;
#pragma unroll
    for (int r = 0; r < 2; ++r){
      int row = r*16 + g16;
      *(short8*)&Xbf[row*X_STRIDE + c8] = *(const short8*)&xb[(row0 + row)*FEAT + c8];
    }
  }
  __syncthreads();
  const int w = tid >> 6, lane = tid & 63;
  const int quad = lane >> 4, mcol = lane & 15;
#pragma unroll
  for (int mt = 0; mt < 2; ++mt){
    floatx4 a0 = {0.f,0.f,0.f,0.f};
    floatx4 a1 = {0.f,0.f,0.f,0.f};
    floatx4 a2 = {0.f,0.f,0.f,0.f};
    floatx4 a3 = {0.f,0.f,0.f,0.f};
#pragma unroll
    for (int ks = 0; ks < 4; ++ks){
      short8 a = *(const short8*)&Xbf[(mt*16 + mcol)*X_STRIDE + ks*32 + quad*8];
      const unsigned short* bp = W1pack + ((w*16 + ks)*64 + lane)*8;
      short8 b0 = *(const short8*)(bp);
      short8 b1 = *(const short8*)(bp + 2048);
      short8 b2 = *(const short8*)(bp + 4096);
      short8 b3 = *(const short8*)(bp + 6144);
      a0 = __builtin_amdgcn_mfma_f32_16x16x32_bf16(a, b0, a0, 0, 0, 0);
      a1 = __builtin_amdgcn_mfma_f32_16x16x32_bf16(a, b1, a1, 0, 0, 0);
      a2 = __builtin_amdgcn_mfma_f32_16x16x32_bf16(a, b2, a2, 0, 0, 0);
      a3 = __builtin_amdgcn_mfma_f32_16x16x32_bf16(a, b3, a3, 0, 0, 0);
    }
#pragma unroll
    for (int nt = 0; nt < 4; ++nt){
      floatx4 acc = (nt == 0) ? a0 : (nt == 1) ? a1 : (nt == 2) ? a2 : a3;
      int n = w*64 + nt*16 + mcol;
#pragma unroll
      for (int reg = 0; reg < 4; ++reg)
        PQb[(row0 + mt*16 + quad*4 + reg)*(2*FEAT) + n] = f2bf_rne(acc[reg]);
    }
  }
}

#define U_STRIDE 136   // bf16 elems

// ---- FUSED: message MLP + LayerNorm + CSR-ordered aggregation ----
// Block = 64 consecutive CSR slots (sorted by target node).
// Phase A: gather P[b]+Q[a], relu -> Ubf (LDS, bf16)
// Phase B: MFMA with W2, relu, per-row LayerNorm -> write bf16 Z back into the
//          SAME LDS tile (aliased; barrier-protected)
// Phase C: 128 threads (one col each) walk the 64 rows; runs of equal target
//          node are reduced and emitted: interior node -> plain store (block
//          owns the node's whole CSR range), boundary node -> atomicAdd.
__global__ __launch_bounds__(256) void k_msgagg(const unsigned short* __restrict__ PQb,
    const unsigned short* __restrict__ W2pack, const float* __restrict__ b1v,
    const float* __restrict__ b2v, const float* __restrict__ ln_g, const float* __restrict__ ln_b,
    const int* __restrict__ idxL, const int* __restrict__ idxR,
    const int* __restrict__ morder, const int* __restrict__ nodeof,
    float* __restrict__ rec){
  __shared__ __align__(16) unsigned short Ubf[64*U_STRIDE];   // aliased U then Z
  __shared__ int sTa[64], sTb[64];
  __shared__ int sEdge[2];   // [0]=node of slot s0-1 (or -1), [1]=node of slot s0+64 (or -1)
  const int tid = threadIdx.x;
  const int s0 = blockIdx.x * 64;
  if (tid < 64){
    int m = morder[s0 + tid];
    int e = (m < N_EDGES) ? m : (m - N_EDGES);
    int l = idxL[e], r = idxR[e];
    sTa[tid] = (m < N_EDGES) ? l : r;
    sTb[tid] = (m < N_EDGES) ? r : l;
  } else if (tid == 64){
    sEdge[0] = (s0 == 0) ? -1 : nodeof[s0 - 1];
  } else if (tid == 65){
    sEdge[1] = (s0 + 64 >= N_MSG) ? -1 : nodeof[s0 + 64];
  }
  __syncthreads();
  {
    const int c8 = (tid & 15)*8, g16 = tid >> 4;
    const float4 b1a = *(const float4*)&b1v[c8];
    const float4 b1b = *(const float4*)&b1v[c8 + 4];
    short8 pb[4], qb[4];
#pragma unroll
    for (int r = 0; r < 4; ++r){
      int row = r*16 + g16;
      pb[r] = *(const short8*)&PQb[sTb[row]*(2*FEAT) + c8];
      qb[r] = *(const short8*)&PQb[sTa[row]*(2*FEAT) + FEAT + c8];
    }
#pragma unroll
    for (int r = 0; r < 4; ++r){
      int row = r*16 + g16;
      ushort4v u0, u1;
      u0.x = f2bf_rne(fmaxf(bf2f(pb[r][0]) + bf2f(qb[r][0]) + b1a.x, 0.f));
      u0.y = f2bf_rne(fmaxf(bf2f(pb[r][1]) + bf2f(qb[r][1]) + b1a.y, 0.f));
      u0.z = f2bf_rne(fmaxf(bf2f(pb[r][2]) + bf2f(qb[r][2]) + b1a.z, 0.f));
      u0.w = f2bf_rne(fmaxf(bf2f(pb[r][3]) + bf2f(qb[r][3]) + b1a.w, 0.f));
      u1.x = f2bf_rne(fmaxf(bf2f(pb[r][4]) + bf2f(qb[r][4]) + b1b.x, 0.f));
      u1.y = f2bf_rne(fmaxf(bf2f(pb[r][5]) + bf2f(qb[r][5]) + b1b.y, 0.f));
      u1.z = f2bf_rne(fmaxf(bf2f(pb[r][6]) + bf2f(qb[r][6]) + b1b.z, 0.f));
      u1.w = f2bf_rne(fmaxf(bf2f(pb[r][7]) + bf2f(qb[r][7]) + b1b.w, 0.f));
      *(ushort4v*)&Ubf[row*U_STRIDE + c8]     = u0;
      *(ushort4v*)&Ubf[row*U_STRIDE + c8 + 4] = u1;
    }
  }
  __syncthreads();
  const int w = tid >> 6, lane = tid & 63;
  const int quad = lane >> 4, mcol = lane & 15;
  const int rbase = w*16;
  floatx4 acc[8];
#pragma unroll
  for (int nt = 0; nt < 8; ++nt) acc[nt] = (floatx4){0.f,0.f,0.f,0.f};
#pragma unroll
  for (int ks = 0; ks < 4; ++ks){
    short8 a = *(const short8*)&Ubf[(rbase + mcol)*U_STRIDE + ks*32 + quad*8];
#pragma unroll
    for (int nt = 0; nt < 8; ++nt){
      short8 b = *(const short8*)(W2pack + ((nt*4 + ks)*64 + lane)*8);
      acc[nt] = __builtin_amdgcn_mfma_f32_16x16x32_bf16(a, b, acc[nt], 0, 0, 0);
    }
  }
  float z[8][4];
#pragma unroll
  for (int nt = 0; nt < 8; ++nt){
    float bb = b2v[nt*16 + mcol];
#pragma unroll
    for (int reg = 0; reg < 4; ++reg) z[nt][reg] = fmaxf(acc[nt][reg] + bb, 0.f);
  }
  float ps[4], pq[4];
#pragma unroll
  for (int reg = 0; reg < 4; ++reg){
    ps[reg] = 0.f; pq[reg] = 0.f;
#pragma unroll
    for (int nt = 0; nt < 8; ++nt){
      ps[reg] += z[nt][reg];
      pq[reg] += z[nt][reg]*z[nt][reg];
    }
  }
#pragma unroll
  for (int o = 1; o < 16; o <<= 1){
#pragma unroll
    for (int reg = 0; reg < 4; ++reg){
      ps[reg] += __shfl_xor(ps[reg], o);
      pq[reg] += __shfl_xor(pq[reg], o);
    }
  }
  float lgv[8], lbv[8];
#pragma unroll
  for (int nt = 0; nt < 8; ++nt){
    lgv[nt] = ln_g[nt*16 + mcol];
    lbv[nt] = ln_b[nt*16 + mcol];
  }
  // normalized outputs -> registers, then overwrite the U tile with Z (bf16)
  unsigned short ob[4][8];
#pragma unroll
  for (int reg = 0; reg < 4; ++reg){
    float mu = ps[reg] * (1.f/FEAT);
    float var = fmaxf(pq[reg] * (1.f/FEAT) - mu*mu, 0.f);
    float rv = rsqrtf(var + EPSF);
#pragma unroll
    for (int nt = 0; nt < 8; ++nt)
      ob[reg][nt] = f2bf_rne(scrub0(lgv[nt]*(z[nt][reg] - mu)*rv + lbv[nt]));
  }
  __syncthreads();   // all waves done reading Ubf -> safe to overwrite
#pragma unroll
  for (int reg = 0; reg < 4; ++reg){
    int row = rbase + quad*4 + reg;
#pragma unroll
    for (int nt = 0; nt < 8; ++nt)
      Ubf[row*U_STRIDE + nt*16 + mcol] = ob[reg][nt];
  }
  __syncthreads();
  // Phase C: segmented sum over sorted rows, one column per thread
  if (tid < 128){
    const int col = tid;
    float accv = 0.f;
    int cur = sTa[0];
    bool part = (sEdge[0] == cur);    // first run continues from prev block
    for (int r = 0; r < 64; ++r){
      accv += bf2f(Ubf[r*U_STRIDE + col]);
      int nxt = (r < 63) ? sTa[r + 1] : -2;
      if (nxt != cur){
        bool tail = (r == 63) && (sEdge[1] == cur);  // run continues into next block
        float* dst = &rec[(size_t)cur*FEAT + col];
        if (part | tail) atomicAdd(dst, accv);
        else *dst = accv;
        accv = 0.f;
        cur = nxt;
        part = false;
      }
    }
  }
}

// ================= fallback path (no CSR) =================
__global__ __launch_bounds__(256) void k_edge(const unsigned short* __restrict__ PQb,
    const unsigned short* __restrict__ W2pack, const float* __restrict__ b1v,
    const float* __restrict__ b2v, const float* __restrict__ ln_g, const float* __restrict__ ln_b,
    const int* __restrict__ idxL, const int* __restrict__ idxR,
    float* __restrict__ agg){
  __shared__ __align__(16) unsigned short Ubf[32*U_STRIDE];
  __shared__ float sS[64], sQ[64];
  __shared__ int sTa[32], sTb[32];
  const int tid = threadIdx.x;
  const int m0 = blockIdx.x * 32;
  if (tid < 32){
    int m = m0 + tid;
    int e = (m < N_EDGES) ? m : (m - N_EDGES);
    int l = idxL[e], r = idxR[e];
    sTa[tid] = (m < N_EDGES) ? l : r;
    sTb[tid] = (m < N_EDGES) ? r : l;
  }
  __syncthreads();
  {
    const int c8 = (tid & 15)*8, g16 = tid >> 4;
    const float4 b1a = *(const float4*)&b1v[c8];
    const float4 b1b = *(const float4*)&b1v[c8 + 4];
#pragma unroll
    for (int r = 0; r < 2; ++r){
      int row = r*16 + g16;
      short8 pb = *(const short8*)&PQb[sTb[row]*(2*FEAT) + c8];
      short8 qb = *(const short8*)&PQb[sTa[row]*(2*FEAT) + FEAT + c8];
      ushort4v u0, u1;
      u0.x = f2bf_rne(fmaxf(bf2f(pb[0]) + bf2f(qb[0]) + b1a.x, 0.f));
      u0.y = f2bf_rne(fmaxf(bf2f(pb[1]) + bf2f(qb[1]) + b1a.y, 0.f));
      u0.z = f2bf_rne(fmaxf(bf2f(pb[2]) + bf2f(qb[2]) + b1a.z, 0.f));
      u0.w = f2bf_rne(fmaxf(bf2f(pb[3]) + bf2f(qb[3]) + b1a.w, 0.f));
      u1.x = f2bf_rne(fmaxf(bf2f(pb[4]) + bf2f(qb[4]) + b1b.x, 0.f));
      u1.y = f2bf_rne(fmaxf(bf2f(pb[5]) + bf2f(qb[5]) + b1b.y, 0.f));
      u1.z = f2bf_rne(fmaxf(bf2f(pb[6]) + bf2f(qb[6]) + b1b.z, 0.f));
      u1.w = f2bf_rne(fmaxf(bf2f(pb[7]) + bf2f(qb[7]) + b1b.w, 0.f));
      *(ushort4v*)&Ubf[row*U_STRIDE + c8]     = u0;
      *(ushort4v*)&Ubf[row*U_STRIDE + c8 + 4] = u1;
    }
  }
  __syncthreads();
  const int w = tid >> 6, lane = tid & 63;
  const int mt = w & 1, nhalf = w >> 1;
  const int quad = lane >> 4, mcol = lane & 15;
  floatx4 acc0 = {0.f,0.f,0.f,0.f};
  floatx4 acc1 = {0.f,0.f,0.f,0.f};
  floatx4 acc2 = {0.f,0.f,0.f,0.f};
  floatx4 acc3 = {0.f,0.f,0.f,0.f};
#pragma unroll
  for (int ks = 0; ks < 4; ++ks){
    short8 a = *(const short8*)&Ubf[(mt*16 + mcol)*U_STRIDE + ks*32 + quad*8];
    const unsigned short* bp = W2pack + ((nhalf*4*256) + ks*64 + lane)*8;
    short8 bq0 = *(const short8*)(bp);
    short8 bq1 = *(const short8*)(bp + 2048);
    short8 bq2 = *(const short8*)(bp + 4096);
    short8 bq3 = *(const short8*)(bp + 6144);
    acc0 = __builtin_amdgcn_mfma_f32_16x16x32_bf16(a, bq0, acc0, 0, 0, 0);
    acc1 = __builtin_amdgcn_mfma_f32_16x16x32_bf16(a, bq1, acc1, 0, 0, 0);
    acc2 = __builtin_amdgcn_mfma_f32_16x16x32_bf16(a, bq2, acc2, 0, 0, 0);
    acc3 = __builtin_amdgcn_mfma_f32_16x16x32_bf16(a, bq3, acc3, 0, 0, 0);
  }
  float z[4][4];
#pragma unroll
  for (int nt = 0; nt < 4; ++nt){
    floatx4 a4 = (nt == 0) ? acc0 : (nt == 1) ? acc1 : (nt == 2) ? acc2 : acc3;
    float bb = b2v[nhalf*64 + nt*16 + mcol];
#pragma unroll
    for (int reg = 0; reg < 4; ++reg) z[nt][reg] = fmaxf(a4[reg] + bb, 0.f);
  }
  float ps[4], pq[4];
#pragma unroll
  for (int reg = 0; reg < 4; ++reg){
    ps[reg] = z[0][reg] + z[1][reg] + z[2][reg] + z[3][reg];
    pq[reg] = z[0][reg]*z[0][reg] + z[1][reg]*z[1][reg] + z[2][reg]*z[2][reg] + z[3][reg]*z[3][reg];
  }
#pragma unroll
  for (int o = 1; o < 16; o <<= 1){
#pragma unroll
    for (int reg = 0; reg < 4; ++reg){
      ps[reg] += __shfl_xor(ps[reg], o);
      pq[reg] += __shfl_xor(pq[reg], o);
    }
  }
  if (mcol == 0){
#pragma unroll
    for (int reg = 0; reg < 4; ++reg){
      int row = mt*16 + quad*4 + reg;
      sS[nhalf*32 + row] = ps[reg];
      sQ[nhalf*32 + row] = pq[reg];
    }
  }
  __syncthreads();
  int colv[4]; float lgv[4], lbv[4];
#pragma unroll
  for (int nt = 0; nt < 4; ++nt){
    colv[nt] = nhalf*64 + nt*16 + mcol;
    lgv[nt] = ln_g[colv[nt]];
    lbv[nt] = ln_b[colv[nt]];
  }
#pragma unroll
  for (int reg = 0; reg < 4; ++reg){
    int row = mt*16 + quad*4 + reg;
    float s = sS[row] + sS[32 + row];
    float q = sQ[row] + sQ[32 + row];
    float mu = s * (1.f/FEAT);
    float var = fmaxf(q * (1.f/FEAT) - mu*mu, 0.f);
    float rv = rsqrtf(var + EPSF);
    int a = sTa[row];
#pragma unroll
    for (int nt = 0; nt < 4; ++nt){
      float o = scrub0(lgv[nt]*(z[nt][reg] - mu)*rv + lbv[nt]);
      atomicAdd(&agg[a*FEAT + colv[nt]], o);
    }
  }
}

__global__ __launch_bounds__(256) void k_stats(const float* __restrict__ src,
    const float* __restrict__ degrees, float* __restrict__ red){
  const int tid = threadIdx.x;
  const int j = tid & 127, half_sel = tid >> 7;
  const int n0 = blockIdx.x * 256;
  float s1 = 0.f, s2 = 0.f;
  for (int i = half_sel; i < 256; i += 2){
    int n = n0 + i;
    if (n < N_VARS){
      float v = src[n*FEAT + j] / degrees[n];
      s1 += v;
      s2 += v*v;
    }
  }
  __shared__ float sh1[256], sh2[256];
  sh1[tid] = s1; sh2[tid] = s2;
  __syncthreads();
  if (half_sel == 0){
    atomicAdd(&red[j],       sh1[tid] + sh1[tid+128]);
    atomicAdd(&red[128 + j], sh2[tid] + sh2[tid+128]);
  }
}

// ---- BN apply + logits + softmax + argmax; bf16 state out ----
__global__ __launch_bounds__(256) void k_bn(const float* __restrict__ src,
    const float* __restrict__ degrees, int divide, const float* __restrict__ red,
    const float* __restrict__ bn_g, const float* __restrict__ bn_b,
    const float* __restrict__ Wd, const float* __restrict__ bd,
    unsigned short* __restrict__ state_bf, int* __restrict__ asg,
    float* __restrict__ out_phi, float* __restrict__ out_asg, int t){
  const int w = threadIdx.x >> 6, l = threadIdx.x & 63;
  const int n = blockIdx.x*4 + w;
  const float invN = 1.f / (float)N_VARS;
  float mu0 = red[l]*invN,     mu1 = red[l+64]*invN;
  float v0  = fmaxf(red[128+l]*invN    - mu0*mu0, 0.f);
  float v1  = fmaxf(red[128+l+64]*invN - mu1*mu1, 0.f);
  float rv0 = rsqrtf(v0 + EPSF);
  float rv1 = rsqrtf(v1 + EPSF);
  float dinv = divide ? (1.f / degrees[n]) : 1.f;
  float r0 = src[n*FEAT + l]    * dinv;
  float r1 = src[n*FEAT + l+64] * dinv;
  float s0 = scrub0(bn_g[l]   *(r0 - mu0)*rv0 + bn_b[l]);
  float s1 = scrub0(bn_g[l+64]*(r1 - mu1)*rv1 + bn_b[l+64]);
  state_bf[n*FEAT + l]    = f2bf_rne(s0);
  state_bf[n*FEAT + l+64] = f2bf_rne(s1);
  float p[4];
#pragma unroll
  for (int d = 0; d < 4; ++d)
    p[d] = s0*Wd[l*4 + d] + s1*Wd[(l+64)*4 + d];
#pragma unroll
  for (int o = 32; o > 0; o >>= 1){
#pragma unroll
    for (int d = 0; d < 4; ++d) p[d] += __shfl_xor(p[d], o);
  }
  if (l == 0){
    float lg[4];
#pragma unroll
    for (int d = 0; d < 4; ++d) lg[d] = scrub0(p[d] + bd[d]);
    float mx = fmaxf(fmaxf(lg[0],lg[1]), fmaxf(lg[2],lg[3]));
    float ex[4]; float ssum = 0.f;
#pragma unroll
    for (int d = 0; d < 4; ++d){ ex[d] = expf(lg[d] - mx); ssum += ex[d]; }
    float inv = 1.f / ssum;
    int am = 0; float bv = -1.f;
#pragma unroll
    for (int d = 0; d < 4; ++d){
      float pv = scrub0(ex[d]*inv);
      out_phi[n*12 + t*4 + d] = pv;
      if (pv > bv){ bv = pv; am = d; }
    }
    asg[n*3 + t] = am;
    if (t == 2) out_asg[n] = (float)am;
  }
}

// ---- merged pair-losses + edge-conflicts (blocks >= NB_LOSS do conf) ----
__global__ __launch_bounds__(256) void k_lossconf(const float* __restrict__ phi,
    const int* __restrict__ iL, const int* __restrict__ iR,
    const int* __restrict__ iLp, const int* __restrict__ iRp,
    const float* __restrict__ rel, const float* __restrict__ conf,
    const int* __restrict__ asg, float* __restrict__ out_ec,
    float* __restrict__ part_l1, float* __restrict__ part_l2,
    float* __restrict__ part_conf){
  if (blockIdx.x < NB_LOSS){
    const int m = blockIdx.x*256 + threadIdx.x;
    float p1 = 0.f, p2 = 0.f;
    if (m < N_EDGES*3){
      int e = m/3, tt = m - e*3;
      const float* pl = phi + iL[e]*12 + tt*4;
      const float* pr = phi + iR[e]*12 + tt*4;
      float s = 0.f;
#pragma unroll
      for (int j = 0; j < 4; ++j){
        float tj = 0.f;
#pragma unroll
        for (int i = 0; i < 4; ++i) tj += pl[i]*rel[i*4+j];
        s += tj*pr[j];
      }
      s = scrub0(s); s = fmaxf(s, 1e-35f);
      p1 = -logf(s);
    } else {
      int m2 = m - N_EDGES*3;
      if (m2 < N_CONFP*3){
        int e = m2/3, tt = m2 - e*3;
        const float* pl = phi + iLp[e]*12 + tt*4;
        const float* pr = phi + iRp[e]*12 + tt*4;
        float s = 0.f;
#pragma unroll
        for (int j = 0; j < 4; ++j){
          float tj = 0.f;
#pragma unroll
          for (int i = 0; i < 4; ++i) tj += pl[i]*conf[i*4+j];
          s += tj*pr[j];
        }
        s = scrub0(s); s = fmaxf(s, 1e-35f);
        p2 = -logf(s);
      }
    }
    __shared__ float sh1[256], sh2[256];
    sh1[threadIdx.x] = p1; sh2[threadIdx.x] = p2;
    __syncthreads();
    for (int k = 128; k > 0; k >>= 1){
      if (threadIdx.x < k){
        sh1[threadIdx.x] += sh1[threadIdx.x + k];
        sh2[threadIdx.x] += sh2[threadIdx.x + k];
      }
      __syncthreads();
    }
    if (threadIdx.x == 0){
      part_l1[blockIdx.x] = sh1[0];
      part_l2[blockIdx.x] = sh2[0];
    }
  } else {
    const int bid = blockIdx.x - NB_LOSS;
    const int e = bid*256 + threadIdx.x;
    float c2 = 0.f;
    if (e < N_EDGES){
      int l = iL[e], r = iR[e];
#pragma unroll
      for (int tt = 0; tt < 3; ++tt){
        int ai = asg[l*3+tt] & 3, bi = asg[r*3+tt] & 3;
        float c = scrub0(1.f - rel[ai*4 + bi]);
        out_ec[e*3 + tt] = c;
        if (tt == 2) c2 = c;
      }
    }
    __shared__ float sh[256];
    sh[threadIdx.x] = c2;
    __syncthreads();
    for (int k = 128; k > 0; k >>= 1){
      if (threadIdx.x < k) sh[threadIdx.x] += sh[threadIdx.x + k];
      __syncthreads();
    }
    if (threadIdx.x == 0) part_conf[bid] = sh[0];
  }
}

// ---- final scalar reduce -> out[0], out[1], out[NCONF_SLOT] ----
__global__ __launch_bounds__(256) void k_fin(const float* __restrict__ part_conf,
    const float* __restrict__ part_l1, const float* __restrict__ part_l2,
    float* __restrict__ out){
  const int tid = threadIdx.x;
  float a = 0.f, ca = 0.f, b = 0.f, cb = 0.f, c = 0.f;
  for (int i = tid; i < NB_LOSS; i += 256){
    float y = part_l1[i] - ca; float t = a + y; ca = (t - a) - y; a = t;
    float y2 = part_l2[i] - cb; float t2 = b + y2; cb = (t2 - b) - y2; b = t2;
  }
  for (int i = tid; i < NB_CONF; i += 256) c += part_conf[i];
  __shared__ float sh1[256], sh2[256], sh3[256];
  sh1[tid] = a; sh2[tid] = b; sh3[tid] = c;
  __syncthreads();
  for (int k = 128; k > 0; k >>= 1){
    if (tid < k){
      sh1[tid] += sh1[tid + k];
      sh2[tid] += sh2[tid + k];
      sh3[tid] += sh3[tid + k];
    }
    __syncthreads();
  }
  if (tid == 0){
    out[0] = sh1[0]/(float)N_EDGES + sh2[0]/(10.f*(float)N_CONFP);
    float nc = sh3[0];
    out[NCONF_SLOT] = nc;
    out[1] = nc / (float)N_EDGES;
  }
}

extern "C" void kernel_launch(void* const* d_in, const int* in_sizes, int n_in,
                              void* d_out, int out_size, void* d_ws, size_t ws_size,
                              hipStream_t stream){
  const float* state0  = (const float*)d_in[0];
  const float* W1      = (const float*)d_in[1];
  const float* b1v     = (const float*)d_in[2];
  const float* W2      = (const float*)d_in[3];
  const float* b2v     = (const float*)d_in[4];
  const float* ln_g    = (const float*)d_in[5];
  const float* ln_b    = (const float*)d_in[6];
  const float* bn_g    = (const float*)d_in[7];
  const float* bn_b    = (const float*)d_in[8];
  const float* Wd      = (const float*)d_in[9];
  const float* bd      = (const float*)d_in[10];
  const float* rel     = (const float*)d_in[11];
  const float* confm   = (const float*)d_in[12];
  const float* degrees = (const float*)d_in[13];
  const int* idxL = (const int*)d_in[14];
  const int* idxR = (const int*)d_in[15];
  const int* iLp  = (const int*)d_in[16];
  const int* iRp  = (const int*)d_in[17];

  char* ws = (char*)d_ws;
  unsigned short* state_bf = (unsigned short*)(ws);          // 10,240,000
  unsigned short* PQb  = (unsigned short*)(ws + 10240000);   // 20,480,000
  float*  recagg    = (float*)(ws + 30720000);               // 20,480,000
  int*    asg       = (int*)  (ws + 51200000);               //    480,000
  float*  red       = (float*)(ws + 51840768);               //      1,024
  float*  part_l1   = (float*)(ws + 51841792);               //     14,068
  float*  part_l2   = (float*)(ws + 51855860);               //     14,068
  float*  part_conf = (float*)(ws + 51869928);               //      3,128
  unsigned short* W2pack = (unsigned short*)(ws + 51873056); //     32,768
  unsigned short* W1pack = (unsigned short*)(ws + 51905824); //     65,536
  int*    pos       = (int*)(ws + 51971360);                 //    160,000
  int*    cnt       = (int*)(ws + 52131360);                 //    160,000
  int*    morder    = (int*)(ws + 52291360);                 //  1,600,000
  int*    blk_tot   = (int*)(ws + 53891360);                 //      1,024
  int*    blk_off   = (int*)(ws + 53892384);                 //      1,024
  int*    nodeof    = (int*)(ws + 53893408);                 //  1,600,000
  const int use_csr = (ws_size >= (size_t)55493408) ? 1 : 0;

  float* out     = (float*)d_out;
  float* out_phi = out + 2;
  float* out_ec  = out + 480002;
  float* out_asg = out + 1080002;

  k_prep<<<8, 256, 0, stream>>>(W2, W2pack);
  k_prep_w1<<<16, 256, 0, stream>>>(W1, W1pack);

  if (use_csr){
    k_zero_int<<<NB_STAT, 256, 0, stream>>>(cnt, N_VARS);
    k_hist<<<(N_MSG + 255)/256, 256, 0, stream>>>(idxL, idxR, cnt);
    k_scan1<<<NB_STAT, 256, 0, stream>>>(cnt, pos, blk_tot);
    k_scan2<<<1, 256, 0, stream>>>(blk_tot, blk_off);
    k_scan3<<<NB_STAT, 256, 0, stream>>>(pos, blk_off);
    k_fill<<<(N_MSG + 255)/256, 256, 0, stream>>>(idxL, idxR, pos, morder, nodeof);
  }

  for (int t = 0; t < T_ITERS; ++t){
    k_pq<<<N_VARS/32, 256, 0, stream>>>(state0, state_bf, (t == 0) ? 1 : 0, W1pack, PQb, red);
    k_zero_agg<<<5000, 256, 0, stream>>>((float4*)recagg);
    if (use_csr){
      k_msgagg<<<N_MSG/64, 256, 0, stream>>>(PQb, W2pack, b1v, b2v, ln_g, ln_b,
                                             idxL, idxR, morder, nodeof, recagg);
    } else {
      k_edge<<<N_MSG/32, 256, 0, stream>>>(PQb, W2pack, b1v, b2v, ln_g, ln_b, idxL, idxR, recagg);
    }
    k_stats<<<NB_STAT, 256, 0, stream>>>(recagg, degrees, red);
    k_bn<<<N_VARS/4, 256, 0, stream>>>(recagg, degrees, 1, red, bn_g, bn_b, Wd, bd,
                                       state_bf, asg, out_phi, out_asg, t);
  }
  k_lossconf<<<NB_LOSS + NB_CONF, 256, 0, stream>>>(out_phi, idxL, idxR, iLp, iRp, rel, confm,
                                                    asg, out_ec, part_l1, part_l2, part_conf);
  k_fin<<<1, 256, 0, stream>>>(part_conf, part_l1, part_l2, out);
}

// Round 2
// 563.116 us; speedup vs baseline: 1.1851x; 1.1176x over previous
//
#include <hip/hip_runtime.h>
#include <math.h>

#define N_VARS 40000
#define FEAT 128
#define N_EDGES 200000
#define N_MSG (2*N_EDGES)
#define N_CONFP 100000
#define T_ITERS 3
#define EPSF 1e-5f

#define NB_CONF 782              // ceil(200000/256)
#define NB_LOSS 3517             // ceil(900000/256)
#define NB_STAT 157              // ceil(40000/256)
#define OUT_TOTAL 1120003
#define NCONF_SLOT 1120002       // sequential carve: 1+1+480000+600000+40000

typedef short short8 __attribute__((ext_vector_type(8)));
typedef float floatx4 __attribute__((ext_vector_type(4)));
typedef unsigned short ushort4v __attribute__((ext_vector_type(4)));

__device__ __forceinline__ float scrub0(float x){
  unsigned u = __float_as_uint(x);
  return ((u & 0x7F800000u) == 0x7F800000u) ? 0.f : x;
}
__device__ __forceinline__ unsigned short f2bf_rne(float x){
  unsigned u = __float_as_uint(x);
  u += 0x7FFFu + ((u >> 16) & 1u);
  return (unsigned short)(u >> 16);
}
__device__ __forceinline__ float bf2f(unsigned short h){
  return __uint_as_float(((unsigned)h) << 16);
}
// HW RNE pack: 2 f32 -> packed bf16x2 in one VALU op (no gfx950 builtin)
__device__ __forceinline__ unsigned cvtpk(float lo, float hi){
  unsigned r;
  asm("v_cvt_pk_bf16_f32 %0, %1, %2" : "=v"(r) : "v"(lo), "v"(hi));
  return r;
}

__global__ __launch_bounds__(256) void k_zero_int(int* __restrict__ p, int n){
  int i = blockIdx.x*256 + threadIdx.x;
  if (i < n) p[i] = 0;
}

// ---- CSR build over message ids m in [0,2E): target = m<E ? idxL[m] : idxR[m-E]
__global__ __launch_bounds__(256) void k_hist(const int* __restrict__ idxL,
    const int* __restrict__ idxR, int* __restrict__ cnt){
  int m = blockIdx.x*256 + threadIdx.x;
  if (m < N_MSG){
    int t = (m < N_EDGES) ? idxL[m] : idxR[m - N_EDGES];
    atomicAdd(&cnt[t], 1);
  }
}
__global__ __launch_bounds__(256) void k_scan1(const int* __restrict__ cnt,
    int* __restrict__ pos, int* __restrict__ blk_tot){
  const int tid = threadIdx.x;
  const int idx = blockIdx.x*256 + tid;
  int v = (idx < N_VARS) ? cnt[idx] : 0;
  __shared__ int sh[256];
  sh[tid] = v;
  __syncthreads();
#pragma unroll
  for (int o = 1; o < 256; o <<= 1){
    int add = (tid >= o) ? sh[tid - o] : 0;
    __syncthreads();
    sh[tid] += add;
    __syncthreads();
  }
  if (idx < N_VARS) pos[idx] = sh[tid] - v;
  if (tid == 255) blk_tot[blockIdx.x] = sh[255];
}
__global__ __launch_bounds__(256) void k_scan2(const int* __restrict__ blk_tot,
    int* __restrict__ blk_off){
  const int tid = threadIdx.x;
  int v = (tid < NB_STAT) ? blk_tot[tid] : 0;
  __shared__ int sh[256];
  sh[tid] = v;
  __syncthreads();
#pragma unroll
  for (int o = 1; o < 256; o <<= 1){
    int add = (tid >= o) ? sh[tid - o] : 0;
    __syncthreads();
    sh[tid] += add;
    __syncthreads();
  }
  if (tid < NB_STAT) blk_off[tid] = sh[tid] - v;
}
__global__ __launch_bounds__(256) void k_scan3(int* __restrict__ pos,
    const int* __restrict__ blk_off){
  const int idx = blockIdx.x*256 + threadIdx.x;
  if (idx < N_VARS) pos[idx] += blk_off[blockIdx.x];
}
// fill: writes INVERSE permutation morder[slot]=m and nodeof[slot]=target
__global__ __launch_bounds__(256) void k_fill(const int* __restrict__ idxL,
    const int* __restrict__ idxR, int* __restrict__ pos,
    int* __restrict__ morder, int* __restrict__ nodeof){
  int m = blockIdx.x*256 + threadIdx.x;
  if (m < N_MSG){
    int t = (m < N_EDGES) ? idxL[m] : idxR[m - N_EDGES];
    int slot = atomicAdd(&pos[t], 1);
    morder[slot] = m;
    nodeof[slot] = t;
  }
}

// ---- pack W2 (128x128 f32) into B-fragment-ordered bf16 (8 ntiles) ----
__global__ __launch_bounds__(256) void k_prep(const float* __restrict__ W2,
                                              unsigned short* __restrict__ W2pack){
  int gid = blockIdx.x*256 + threadIdx.x;
  int lane = gid & 63;
  int ks = (gid >> 6) & 3;
  int ntg = gid >> 8;
  int kbase = ks*32 + (lane >> 4)*8;
  int n = ntg*16 + (lane & 15);
#pragma unroll
  for (int j = 0; j < 8; ++j)
    W2pack[gid*8 + j] = f2bf_rne(W2[(kbase + j)*FEAT + n]);
}
__global__ __launch_bounds__(256) void k_prep_w1(const float* __restrict__ W1,
                                                 unsigned short* __restrict__ W1pack){
  int gid = blockIdx.x*256 + threadIdx.x;
  int lane = gid & 63;
  int ks = (gid >> 6) & 3;
  int ntg = gid >> 8;
  int kbase = ks*32 + (lane >> 4)*8;
  int n = ntg*16 + (lane & 15);
#pragma unroll
  for (int j = 0; j < 8; ++j){
    int k = kbase + j;
    float v = (n < 128) ? W1[k*FEAT + n] : W1[(128 + k)*FEAT + (n - 128)];
    W1pack[gid*8 + j] = f2bf_rne(v);
  }
}

// ---- PQ = x @ [W1top | W1bot] via MFMA bf16 -> bf16 store.
// Q-half accumulators init with b1 (bias folded into PQb).
// Also zeroes red (block 0) and the whole recagg buffer (all blocks).
#define X_STRIDE 136
__global__ __launch_bounds__(256) void k_pq(const float* __restrict__ xf,
                                            const unsigned short* __restrict__ xb,
                                            int src_f32,
                                            const unsigned short* __restrict__ W1pack,
                                            const float* __restrict__ b1v,
                                            unsigned short* __restrict__ PQb,
                                            float* __restrict__ red,
                                            float4* __restrict__ recz){
  __shared__ __align__(16) unsigned short Xbf[32*X_STRIDE];
  const int tid = threadIdx.x;
  const int row0 = blockIdx.x * 32;
  if (blockIdx.x == 0) red[tid] = 0.f;
  {  // zero recagg: 1250 blocks * 256 threads * 4 float4 = 1,280,000 float4
    const int zid = blockIdx.x*256 + tid;
#pragma unroll
    for (int i = 0; i < 4; ++i)
      recz[zid + i*320000] = make_float4(0.f,0.f,0.f,0.f);
  }
  if (src_f32){
    const int c4 = (tid & 31)*4, g8 = tid >> 5;
#pragma unroll
    for (int r = 0; r < 4; ++r){
      int row = g8*4 + r;
      const float4 v = *(const float4*)&xf[(row0 + row)*FEAT + c4];
      uint2 uu;
      uu.x = cvtpk(v.x, v.y);
      uu.y = cvtpk(v.z, v.w);
      *(uint2*)&Xbf[row*X_STRIDE + c4] = uu;
    }
  } else {
    const int c8 = (tid & 15)*8, g16 = tid >> 4;
#pragma unroll
    for (int r = 0; r < 2; ++r){
      int row = r*16 + g16;
      *(short8*)&Xbf[row*X_STRIDE + c8] = *(const short8*)&xb[(row0 + row)*FEAT + c8];
    }
  }
  __syncthreads();
  const int w = tid >> 6, lane = tid & 63;
  const int quad = lane >> 4, mcol = lane & 15;
  float bi0 = 0.f, bi1 = 0.f, bi2 = 0.f, bi3 = 0.f;
  if (w >= 2){
    int nb = (w - 2)*64 + mcol;
    bi0 = b1v[nb]; bi1 = b1v[nb + 16]; bi2 = b1v[nb + 32]; bi3 = b1v[nb + 48];
  }
#pragma unroll
  for (int mt = 0; mt < 2; ++mt){
    floatx4 a0 = {bi0,bi0,bi0,bi0};
    floatx4 a1 = {bi1,bi1,bi1,bi1};
    floatx4 a2 = {bi2,bi2,bi2,bi2};
    floatx4 a3 = {bi3,bi3,bi3,bi3};
#pragma unroll
    for (int ks = 0; ks < 4; ++ks){
      short8 a = *(const short8*)&Xbf[(mt*16 + mcol)*X_STRIDE + ks*32 + quad*8];
      const unsigned short* bp = W1pack + ((w*16 + ks)*64 + lane)*8;
      short8 b0 = *(const short8*)(bp);
      short8 b1 = *(const short8*)(bp + 2048);
      short8 b2 = *(const short8*)(bp + 4096);
      short8 b3 = *(const short8*)(bp + 6144);
      a0 = __builtin_amdgcn_mfma_f32_16x16x32_bf16(a, b0, a0, 0, 0, 0);
      a1 = __builtin_amdgcn_mfma_f32_16x16x32_bf16(a, b1, a1, 0, 0, 0);
      a2 = __builtin_amdgcn_mfma_f32_16x16x32_bf16(a, b2, a2, 0, 0, 0);
      a3 = __builtin_amdgcn_mfma_f32_16x16x32_bf16(a, b3, a3, 0, 0, 0);
    }
#pragma unroll
    for (int reg = 0; reg < 4; ++reg){
      unsigned u01 = cvtpk(a0[reg], a1[reg]);
      unsigned u23 = cvtpk(a2[reg], a3[reg]);
      size_t base = (size_t)(row0 + mt*16 + quad*4 + reg)*(2*FEAT) + w*64 + mcol;
      PQb[base]      = (unsigned short)u01;
      PQb[base + 16] = (unsigned short)(u01 >> 16);
      PQb[base + 32] = (unsigned short)u23;
      PQb[base + 48] = (unsigned short)(u23 >> 16);
    }
  }
}

#define U_STRIDE 136   // bf16 elems (phase A/B row-major layout)
#define ZT_STRIDE 68   // f16 elems (phase C col-major layout, aliased)

// ---- FUSED: message MLP + LayerNorm + CSR-ordered aggregation ----
// Phase A: gather P[b]+Q'[a] (b1 pre-folded), relu -> Ubf (LDS bf16, cvt_pk)
// Phase B: MFMA with W2 (b2 in acc init), relu, per-row LayerNorm
// Phase B': write bf16 Z TRANSPOSED into the same LDS tile (col-major, pad 68)
// Phase C: all 256 threads; col=tid&127, half=tid>>7 walks 32 rows loaded with
//          8 vector ds_reads; runs of equal target emitted *1/deg; runs that
//          touch a half/block boundary use atomicAdd, interior runs plain store.
__global__ __launch_bounds__(256) void k_msgagg(const unsigned short* __restrict__ PQb,
    const unsigned short* __restrict__ W2pack,
    const float* __restrict__ b2v, const float* __restrict__ ln_g, const float* __restrict__ ln_b,
    const int* __restrict__ idxL, const int* __restrict__ idxR,
    const int* __restrict__ morder, const int* __restrict__ nodeof,
    const float* __restrict__ degrees,
    float* __restrict__ rec){
  __shared__ __align__(16) unsigned short Ubf[64*U_STRIDE];   // aliased U then Z^T
  __shared__ int sTa[64], sTb[64];
  __shared__ float sDinv[64];
  __shared__ int sEdge[2];   // [0]=node of slot s0-1 (or -1), [1]=node of slot s0+64 (or -1)
  const int tid = threadIdx.x;
  const int s0 = blockIdx.x * 64;
  if (tid < 64){
    int m = morder[s0 + tid];
    int e = (m < N_EDGES) ? m : (m - N_EDGES);
    int l = idxL[e], r = idxR[e];
    int ta = (m < N_EDGES) ? l : r;
    sTa[tid] = ta;
    sTb[tid] = (m < N_EDGES) ? r : l;
    sDinv[tid] = 1.f / degrees[ta];
  } else if (tid == 64){
    sEdge[0] = (s0 == 0) ? -1 : nodeof[s0 - 1];
  } else if (tid == 65){
    sEdge[1] = (s0 + 64 >= N_MSG) ? -1 : nodeof[s0 + 64];
  }
  __syncthreads();
  {
    const int c8 = (tid & 15)*8, g16 = tid >> 4;
    short8 pb[4], qb[4];
#pragma unroll
    for (int r = 0; r < 4; ++r){
      int row = r*16 + g16;
      pb[r] = *(const short8*)&PQb[sTb[row]*(2*FEAT) + c8];
      qb[r] = *(const short8*)&PQb[sTa[row]*(2*FEAT) + FEAT + c8];
    }
#pragma unroll
    for (int r = 0; r < 4; ++r){
      int row = r*16 + g16;
      float f[8];
#pragma unroll
      for (int j = 0; j < 8; ++j)
        f[j] = fmaxf(bf2f((unsigned short)pb[r][j]) + bf2f((unsigned short)qb[r][j]), 0.f);
      uint4 uu;
      uu.x = cvtpk(f[0], f[1]);
      uu.y = cvtpk(f[2], f[3]);
      uu.z = cvtpk(f[4], f[5]);
      uu.w = cvtpk(f[6], f[7]);
      *(uint4*)&Ubf[row*U_STRIDE + c8] = uu;
    }
  }
  __syncthreads();
  const int w = tid >> 6, lane = tid & 63;
  const int quad = lane >> 4, mcol = lane & 15;
  const int rbase = w*16;
  floatx4 acc[8];
#pragma unroll
  for (int nt = 0; nt < 8; ++nt){
    float b = b2v[nt*16 + mcol];
    acc[nt] = (floatx4){b, b, b, b};
  }
#pragma unroll
  for (int ks = 0; ks < 4; ++ks){
    short8 a = *(const short8*)&Ubf[(rbase + mcol)*U_STRIDE + ks*32 + quad*8];
#pragma unroll
    for (int nt = 0; nt < 8; ++nt){
      short8 b = *(const short8*)(W2pack + ((nt*4 + ks)*64 + lane)*8);
      acc[nt] = __builtin_amdgcn_mfma_f32_16x16x32_bf16(a, b, acc[nt], 0, 0, 0);
    }
  }
  float z[8][4];
#pragma unroll
  for (int nt = 0; nt < 8; ++nt){
#pragma unroll
    for (int reg = 0; reg < 4; ++reg) z[nt][reg] = fmaxf(acc[nt][reg], 0.f);
  }
  float ps[4], pq[4];
#pragma unroll
  for (int reg = 0; reg < 4; ++reg){
    ps[reg] = 0.f; pq[reg] = 0.f;
#pragma unroll
    for (int nt = 0; nt < 8; ++nt){
      ps[reg] += z[nt][reg];
      pq[reg] += z[nt][reg]*z[nt][reg];
    }
  }
#pragma unroll
  for (int o = 1; o < 16; o <<= 1){
#pragma unroll
    for (int reg = 0; reg < 4; ++reg){
      ps[reg] += __shfl_xor(ps[reg], o);
      pq[reg] += __shfl_xor(pq[reg], o);
    }
  }
  float lgv[8], lbv[8];
#pragma unroll
  for (int nt = 0; nt < 8; ++nt){
    lgv[nt] = ln_g[nt*16 + mcol];
    lbv[nt] = ln_b[nt*16 + mcol];
  }
  // LN outputs -> packed bf16 pairs in registers
  unsigned obp[4][4];
#pragma unroll
  for (int reg = 0; reg < 4; ++reg){
    float mu = ps[reg] * (1.f/FEAT);
    float var = fmaxf(pq[reg] * (1.f/FEAT) - mu*mu, 0.f);
    float rv = rsqrtf(var + EPSF);
#pragma unroll
    for (int np = 0; np < 4; ++np){
      float o0 = scrub0(lgv[2*np  ]*(z[2*np  ][reg] - mu)*rv + lbv[2*np  ]);
      float o1 = scrub0(lgv[2*np+1]*(z[2*np+1][reg] - mu)*rv + lbv[2*np+1]);
      obp[reg][np] = cvtpk(o0, o1);
    }
  }
  __syncthreads();   // all waves done reading Ubf -> safe to overwrite (as Z^T)
#pragma unroll
  for (int reg = 0; reg < 4; ++reg){
    int row = rbase + quad*4 + reg;
#pragma unroll
    for (int np = 0; np < 4; ++np){
      unsigned u = obp[reg][np];
      Ubf[(2*np*16 + mcol)*ZT_STRIDE + row]       = (unsigned short)u;
      Ubf[((2*np+1)*16 + mcol)*ZT_STRIDE + row]   = (unsigned short)(u >> 16);
    }
  }
  __syncthreads();
  // Phase C: segmented sum over sorted rows; 2 halves x 128 cols
  {
    const int col = tid & 127, h = tid >> 7;
    const int rbeg = h*32;
    ushort4v rv4[8];
#pragma unroll
    for (int k = 0; k < 8; ++k)
      rv4[k] = *(const ushort4v*)&Ubf[col*ZT_STRIDE + rbeg + k*4];
    float accv = 0.f;
    int cur = sTa[rbeg];
    bool part = (rbeg == 0) ? (sEdge[0] == cur) : (sTa[rbeg-1] == cur);
#pragma unroll
    for (int i = 0; i < 32; ++i){
      accv += bf2f((unsigned short)rv4[i >> 2][i & 3]);
      const int r = rbeg + i;
      int nxt = (r < 63) ? sTa[r + 1] : -2;
      const bool lastr = (i == 31);
      if (lastr | (nxt != cur)){
        bool tail = lastr && ((r == 63) ? (sEdge[1] == cur) : (nxt == cur));
        float v = accv * sDinv[r];
        float* dst = &rec[(size_t)cur*FEAT + col];
        if (part | tail) atomicAdd(dst, v);
        else *dst = v;
        accv = 0.f;
        cur = nxt;
        part = false;
      }
    }
  }
}

// ================= fallback path (no CSR) =================
__global__ __launch_bounds__(256) void k_edge(const unsigned short* __restrict__ PQb,
    const unsigned short* __restrict__ W2pack,
    const float* __restrict__ b2v, const float* __restrict__ ln_g, const float* __restrict__ ln_b,
    const int* __restrict__ idxL, const int* __restrict__ idxR,
    float* __restrict__ agg){
  __shared__ __align__(16) unsigned short Ubf[32*U_STRIDE];
  __shared__ float sS[64], sQ[64];
  __shared__ int sTa[32], sTb[32];
  const int tid = threadIdx.x;
  const int m0 = blockIdx.x * 32;
  if (tid < 32){
    int m = m0 + tid;
    int e = (m < N_EDGES) ? m : (m - N_EDGES);
    int l = idxL[e], r = idxR[e];
    sTa[tid] = (m < N_EDGES) ? l : r;
    sTb[tid] = (m < N_EDGES) ? r : l;
  }
  __syncthreads();
  {
    const int c8 = (tid & 15)*8, g16 = tid >> 4;
#pragma unroll
    for (int r = 0; r < 2; ++r){
      int row = r*16 + g16;
      short8 pb = *(const short8*)&PQb[sTb[row]*(2*FEAT) + c8];
      short8 qb = *(const short8*)&PQb[sTa[row]*(2*FEAT) + FEAT + c8];
      float f[8];
#pragma unroll
      for (int j = 0; j < 8; ++j)
        f[j] = fmaxf(bf2f((unsigned short)pb[j]) + bf2f((unsigned short)qb[j]), 0.f);
      uint4 uu;
      uu.x = cvtpk(f[0], f[1]);
      uu.y = cvtpk(f[2], f[3]);
      uu.z = cvtpk(f[4], f[5]);
      uu.w = cvtpk(f[6], f[7]);
      *(uint4*)&Ubf[row*U_STRIDE + c8] = uu;
    }
  }
  __syncthreads();
  const int w = tid >> 6, lane = tid & 63;
  const int mt = w & 1, nhalf = w >> 1;
  const int quad = lane >> 4, mcol = lane & 15;
  float bb0 = b2v[nhalf*64 + 0*16 + mcol];
  float bb1 = b2v[nhalf*64 + 1*16 + mcol];
  float bb2 = b2v[nhalf*64 + 2*16 + mcol];
  float bb3 = b2v[nhalf*64 + 3*16 + mcol];
  floatx4 acc0 = {bb0,bb0,bb0,bb0};
  floatx4 acc1 = {bb1,bb1,bb1,bb1};
  floatx4 acc2 = {bb2,bb2,bb2,bb2};
  floatx4 acc3 = {bb3,bb3,bb3,bb3};
#pragma unroll
  for (int ks = 0; ks < 4; ++ks){
    short8 a = *(const short8*)&Ubf[(mt*16 + mcol)*U_STRIDE + ks*32 + quad*8];
    const unsigned short* bp = W2pack + ((nhalf*4*256) + ks*64 + lane)*8;
    short8 bq0 = *(const short8*)(bp);
    short8 bq1 = *(const short8*)(bp + 2048);
    short8 bq2 = *(const short8*)(bp + 4096);
    short8 bq3 = *(const short8*)(bp + 6144);
    acc0 = __builtin_amdgcn_mfma_f32_16x16x32_bf16(a, bq0, acc0, 0, 0, 0);
    acc1 = __builtin_amdgcn_mfma_f32_16x16x32_bf16(a, bq1, acc1, 0, 0, 0);
    acc2 = __builtin_amdgcn_mfma_f32_16x16x32_bf16(a, bq2, acc2, 0, 0, 0);
    acc3 = __builtin_amdgcn_mfma_f32_16x16x32_bf16(a, bq3, acc3, 0, 0, 0);
  }
  float z[4][4];
#pragma unroll
  for (int nt = 0; nt < 4; ++nt){
    floatx4 a4 = (nt == 0) ? acc0 : (nt == 1) ? acc1 : (nt == 2) ? acc2 : acc3;
#pragma unroll
    for (int reg = 0; reg < 4; ++reg) z[nt][reg] = fmaxf(a4[reg], 0.f);
  }
  float ps[4], pq[4];
#pragma unroll
  for (int reg = 0; reg < 4; ++reg){
    ps[reg] = z[0][reg] + z[1][reg] + z[2][reg] + z[3][reg];
    pq[reg] = z[0][reg]*z[0][reg] + z[1][reg]*z[1][reg] + z[2][reg]*z[2][reg] + z[3][reg]*z[3][reg];
  }
#pragma unroll
  for (int o = 1; o < 16; o <<= 1){
#pragma unroll
    for (int reg = 0; reg < 4; ++reg){
      ps[reg] += __shfl_xor(ps[reg], o);
      pq[reg] += __shfl_xor(pq[reg], o);
    }
  }
  if (mcol == 0){
#pragma unroll
    for (int reg = 0; reg < 4; ++reg){
      int row = mt*16 + quad*4 + reg;
      sS[nhalf*32 + row] = ps[reg];
      sQ[nhalf*32 + row] = pq[reg];
    }
  }
  __syncthreads();
  int colv[4]; float lgv[4], lbv[4];
#pragma unroll
  for (int nt = 0; nt < 4; ++nt){
    colv[nt] = nhalf*64 + nt*16 + mcol;
    lgv[nt] = ln_g[colv[nt]];
    lbv[nt] = ln_b[colv[nt]];
  }
#pragma unroll
  for (int reg = 0; reg < 4; ++reg){
    int row = mt*16 + quad*4 + reg;
    float s = sS[row] + sS[32 + row];
    float q = sQ[row] + sQ[32 + row];
    float mu = s * (1.f/FEAT);
    float var = fmaxf(q * (1.f/FEAT) - mu*mu, 0.f);
    float rv = rsqrtf(var + EPSF);
    int a = sTa[row];
#pragma unroll
    for (int nt = 0; nt < 4; ++nt){
      float o = scrub0(lgv[nt]*(z[nt][reg] - mu)*rv + lbv[nt]);
      atomicAdd(&agg[a*FEAT + colv[nt]], o);
    }
  }
}

__global__ __launch_bounds__(256) void k_stats(const float* __restrict__ src,
    const float* __restrict__ degrees, int divide, float* __restrict__ red){
  const int tid = threadIdx.x;
  const int j = tid & 127, half_sel = tid >> 7;
  const int n0 = blockIdx.x * 256;
  float s1 = 0.f, s2 = 0.f;
  for (int i = half_sel; i < 256; i += 2){
    int n = n0 + i;
    if (n < N_VARS){
      float v = src[n*FEAT + j];
      if (divide) v /= degrees[n];
      s1 += v;
      s2 += v*v;
    }
  }
  __shared__ float sh1[256], sh2[256];
  sh1[tid] = s1; sh2[tid] = s2;
  __syncthreads();
  if (half_sel == 0){
    atomicAdd(&red[j],       sh1[tid] + sh1[tid+128]);
    atomicAdd(&red[128 + j], sh2[tid] + sh2[tid+128]);
  }
}

// ---- BN apply + logits + softmax + argmax; bf16 state out ----
__global__ __launch_bounds__(256) void k_bn(const float* __restrict__ src,
    const float* __restrict__ degrees, int divide, const float* __restrict__ red,
    const float* __restrict__ bn_g, const float* __restrict__ bn_b,
    const float* __restrict__ Wd, const float* __restrict__ bd,
    unsigned short* __restrict__ state_bf, int* __restrict__ asg,
    float* __restrict__ out_phi, float* __restrict__ out_asg, int t){
  const int w = threadIdx.x >> 6, l = threadIdx.x & 63;
  const int n = blockIdx.x*4 + w;
  const float invN = 1.f / (float)N_VARS;
  float mu0 = red[l]*invN,     mu1 = red[l+64]*invN;
  float v0  = fmaxf(red[128+l]*invN    - mu0*mu0, 0.f);
  float v1  = fmaxf(red[128+l+64]*invN - mu1*mu1, 0.f);
  float rv0 = rsqrtf(v0 + EPSF);
  float rv1 = rsqrtf(v1 + EPSF);
  float dinv = divide ? (1.f / degrees[n]) : 1.f;
  float r0 = src[n*FEAT + l]    * dinv;
  float r1 = src[n*FEAT + l+64] * dinv;
  float s0 = scrub0(bn_g[l]   *(r0 - mu0)*rv0 + bn_b[l]);
  float s1 = scrub0(bn_g[l+64]*(r1 - mu1)*rv1 + bn_b[l+64]);
  state_bf[n*FEAT + l]    = f2bf_rne(s0);
  state_bf[n*FEAT + l+64] = f2bf_rne(s1);
  float p[4];
#pragma unroll
  for (int d = 0; d < 4; ++d)
    p[d] = s0*Wd[l*4 + d] + s1*Wd[(l+64)*4 + d];
#pragma unroll
  for (int o = 32; o > 0; o >>= 1){
#pragma unroll
    for (int d = 0; d < 4; ++d) p[d] += __shfl_xor(p[d], o);
  }
  if (l == 0){
    float lg[4];
#pragma unroll
    for (int d = 0; d < 4; ++d) lg[d] = scrub0(p[d] + bd[d]);
    float mx = fmaxf(fmaxf(lg[0],lg[1]), fmaxf(lg[2],lg[3]));
    float ex[4]; float ssum = 0.f;
#pragma unroll
    for (int d = 0; d < 4; ++d){ ex[d] = expf(lg[d] - mx); ssum += ex[d]; }
    float inv = 1.f / ssum;
    int am = 0; float bv = -1.f;
#pragma unroll
    for (int d = 0; d < 4; ++d){
      float pv = scrub0(ex[d]*inv);
      out_phi[n*12 + t*4 + d] = pv;
      if (pv > bv){ bv = pv; am = d; }
    }
    asg[n*3 + t] = am;
    if (t == 2) out_asg[n] = (float)am;
  }
}

// ---- merged pair-losses + edge-conflicts (blocks >= NB_LOSS do conf) ----
__global__ __launch_bounds__(256) void k_lossconf(const float* __restrict__ phi,
    const int* __restrict__ iL, const int* __restrict__ iR,
    const int* __restrict__ iLp, const int* __restrict__ iRp,
    const float* __restrict__ rel, const float* __restrict__ conf,
    const int* __restrict__ asg, float* __restrict__ out_ec,
    float* __restrict__ part_l1, float* __restrict__ part_l2,
    float* __restrict__ part_conf){
  if (blockIdx.x < NB_LOSS){
    const int m = blockIdx.x*256 + threadIdx.x;
    float p1 = 0.f, p2 = 0.f;
    if (m < N_EDGES*3){
      int e = m/3, tt = m - e*3;
      const float* pl = phi + iL[e]*12 + tt*4;
      const float* pr = phi + iR[e]*12 + tt*4;
      float s = 0.f;
#pragma unroll
      for (int j = 0; j < 4; ++j){
        float tj = 0.f;
#pragma unroll
        for (int i = 0; i < 4; ++i) tj += pl[i]*rel[i*4+j];
        s += tj*pr[j];
      }
      s = scrub0(s); s = fmaxf(s, 1e-35f);
      p1 = -logf(s);
    } else {
      int m2 = m - N_EDGES*3;
      if (m2 < N_CONFP*3){
        int e = m2/3, tt = m2 - e*3;
        const float* pl = phi + iLp[e]*12 + tt*4;
        const float* pr = phi + iRp[e]*12 + tt*4;
        float s = 0.f;
#pragma unroll
        for (int j = 0; j < 4; ++j){
          float tj = 0.f;
#pragma unroll
          for (int i = 0; i < 4; ++i) tj += pl[i]*conf[i*4+j];
          s += tj*pr[j];
        }
        s = scrub0(s); s = fmaxf(s, 1e-35f);
        p2 = -logf(s);
      }
    }
    __shared__ float sh1[256], sh2[256];
    sh1[threadIdx.x] = p1; sh2[threadIdx.x] = p2;
    __syncthreads();
    for (int k = 128; k > 0; k >>= 1){
      if (threadIdx.x < k){
        sh1[threadIdx.x] += sh1[threadIdx.x + k];
        sh2[threadIdx.x] += sh2[threadIdx.x + k];
      }
      __syncthreads();
    }
    if (threadIdx.x == 0){
      part_l1[blockIdx.x] = sh1[0];
      part_l2[blockIdx.x] = sh2[0];
    }
  } else {
    const int bid = blockIdx.x - NB_LOSS;
    const int e = bid*256 + threadIdx.x;
    float c2 = 0.f;
    if (e < N_EDGES){
      int l = iL[e], r = iR[e];
#pragma unroll
      for (int tt = 0; tt < 3; ++tt){
        int ai = asg[l*3+tt] & 3, bi = asg[r*3+tt] & 3;
        float c = scrub0(1.f - rel[ai*4 + bi]);
        out_ec[e*3 + tt] = c;
        if (tt == 2) c2 = c;
      }
    }
    __shared__ float sh[256];
    sh[threadIdx.x] = c2;
    __syncthreads();
    for (int k = 128; k > 0; k >>= 1){
      if (threadIdx.x < k) sh[threadIdx.x] += sh[threadIdx.x + k];
      __syncthreads();
    }
    if (threadIdx.x == 0) part_conf[bid] = sh[0];
  }
}

// ---- final scalar reduce -> out[0], out[1], out[NCONF_SLOT] ----
__global__ __launch_bounds__(256) void k_fin(const float* __restrict__ part_conf,
    const float* __restrict__ part_l1, const float* __restrict__ part_l2,
    float* __restrict__ out){
  const int tid = threadIdx.x;
  float a = 0.f, ca = 0.f, b = 0.f, cb = 0.f, c = 0.f;
  for (int i = tid; i < NB_LOSS; i += 256){
    float y = part_l1[i] - ca; float t = a + y; ca = (t - a) - y; a = t;
    float y2 = part_l2[i] - cb; float t2 = b + y2; cb = (t2 - b) - y2; b = t2;
  }
  for (int i = tid; i < NB_CONF; i += 256) c += part_conf[i];
  __shared__ float sh1[256], sh2[256], sh3[256];
  sh1[tid] = a; sh2[tid] = b; sh3[tid] = c;
  __syncthreads();
  for (int k = 128; k > 0; k >>= 1){
    if (tid < k){
      sh1[tid] += sh1[tid + k];
      sh2[tid] += sh2[tid + k];
      sh3[tid] += sh3[tid + k];
    }
    __syncthreads();
  }
  if (tid == 0){
    out[0] = sh1[0]/(float)N_EDGES + sh2[0]/(10.f*(float)N_CONFP);
    float nc = sh3[0];
    out[NCONF_SLOT] = nc;
    out[1] = nc / (float)N_EDGES;
  }
}

extern "C" void kernel_launch(void* const* d_in, const int* in_sizes, int n_in,
                              void* d_out, int out_size, void* d_ws, size_t ws_size,
                              hipStream_t stream){
  const float* state0  = (const float*)d_in[0];
  const float* W1      = (const float*)d_in[1];
  const float* b1v     = (const float*)d_in[2];
  const float* W2      = (const float*)d_in[3];
  const float* b2v     = (const float*)d_in[4];
  const float* ln_g    = (const float*)d_in[5];
  const float* ln_b    = (const float*)d_in[6];
  const float* bn_g    = (const float*)d_in[7];
  const float* bn_b    = (const float*)d_in[8];
  const float* Wd      = (const float*)d_in[9];
  const float* bd      = (const float*)d_in[10];
  const float* rel     = (const float*)d_in[11];
  const float* confm   = (const float*)d_in[12];
  const float* degrees = (const float*)d_in[13];
  const int* idxL = (const int*)d_in[14];
  const int* idxR = (const int*)d_in[15];
  const int* iLp  = (const int*)d_in[16];
  const int* iRp  = (const int*)d_in[17];

  char* ws = (char*)d_ws;
  unsigned short* state_bf = (unsigned short*)(ws);          // 10,240,000
  unsigned short* PQb  = (unsigned short*)(ws + 10240000);   // 20,480,000
  float*  recagg    = (float*)(ws + 30720000);               // 20,480,000
  int*    asg       = (int*)  (ws + 51200000);               //    480,000
  float*  red       = (float*)(ws + 51840768);               //      1,024
  float*  part_l1   = (float*)(ws + 51841792);               //     14,068
  float*  part_l2   = (float*)(ws + 51855860);               //     14,068
  float*  part_conf = (float*)(ws + 51869928);               //      3,128
  unsigned short* W2pack = (unsigned short*)(ws + 51873056); //     32,768
  unsigned short* W1pack = (unsigned short*)(ws + 51905824); //     65,536
  int*    pos       = (int*)(ws + 51971360);                 //    160,000
  int*    cnt       = (int*)(ws + 52131360);                 //    160,000
  int*    morder    = (int*)(ws + 52291360);                 //  1,600,000
  int*    blk_tot   = (int*)(ws + 53891360);                 //      1,024
  int*    blk_off   = (int*)(ws + 53892384);                 //      1,024
  int*    nodeof    = (int*)(ws + 53893408);                 //  1,600,000
  const int use_csr = (ws_size >= (size_t)55493408) ? 1 : 0;

  float* out     = (float*)d_out;
  float* out_phi = out + 2;
  float* out_ec  = out + 480002;
  float* out_asg = out + 1080002;

  k_prep<<<8, 256, 0, stream>>>(W2, W2pack);
  k_prep_w1<<<16, 256, 0, stream>>>(W1, W1pack);

  if (use_csr){
    k_zero_int<<<NB_STAT, 256, 0, stream>>>(cnt, N_VARS);
    k_hist<<<(N_MSG + 255)/256, 256, 0, stream>>>(idxL, idxR, cnt);
    k_scan1<<<NB_STAT, 256, 0, stream>>>(cnt, pos, blk_tot);
    k_scan2<<<1, 256, 0, stream>>>(blk_tot, blk_off);
    k_scan3<<<NB_STAT, 256, 0, stream>>>(pos, blk_off);
    k_fill<<<(N_MSG + 255)/256, 256, 0, stream>>>(idxL, idxR, pos, morder, nodeof);
  }

  for (int t = 0; t < T_ITERS; ++t){
    k_pq<<<N_VARS/32, 256, 0, stream>>>(state0, state_bf, (t == 0) ? 1 : 0, W1pack, b1v,
                                        PQb, red, (float4*)recagg);
    if (use_csr){
      k_msgagg<<<N_MSG/64, 256, 0, stream>>>(PQb, W2pack, b2v, ln_g, ln_b,
                                             idxL, idxR, morder, nodeof, degrees, recagg);
      k_stats<<<NB_STAT, 256, 0, stream>>>(recagg, degrees, 0, red);
      k_bn<<<N_VARS/4, 256, 0, stream>>>(recagg, degrees, 0, red, bn_g, bn_b, Wd, bd,
                                         state_bf, asg, out_phi, out_asg, t);
    } else {
      k_edge<<<N_MSG/32, 256, 0, stream>>>(PQb, W2pack, b2v, ln_g, ln_b, idxL, idxR, recagg);
      k_stats<<<NB_STAT, 256, 0, stream>>>(recagg, degrees, 1, red);
      k_bn<<<N_VARS/4, 256, 0, stream>>>(recagg, degrees, 1, red, bn_g, bn_b, Wd, bd,
                                         state_bf, asg, out_phi, out_asg, t);
    }
  }
  k_lossconf<<<NB_LOSS + NB_CONF, 256, 0, stream>>>(out_phi, idxL, idxR, iLp, iRp, rel, confm,
                                                    asg, out_ec, part_l1, part_l2, part_conf);
  k_fin<<<1, 256, 0, stream>>>(part_conf, part_l1, part_l2, out);
}

// Round 3
// 523.417 us; speedup vs baseline: 1.2750x; 1.0758x over previous
//
#include <hip/hip_runtime.h>
#include <math.h>

#define N_VARS 40000
#define FEAT 128
#define N_EDGES 200000
#define N_MSG (2*N_EDGES)
#define N_CONFP 100000
#define T_ITERS 3
#define EPSF 1e-5f

#define NB_CONF 782              // ceil(200000/256)
#define NB_PAIR 1172             // ceil(300000/256): 1 thread/edge, 3 t each
#define NB_STAT 157              // ceil(40000/256)  (scan kernels)
#define NB_STAT2 625             // 40000/64 (stats kernel)
#define OUT_TOTAL 1120003
#define NCONF_SLOT 1120002       // sequential carve: 1+1+480000+600000+40000

typedef short short8 __attribute__((ext_vector_type(8)));
typedef float floatx4 __attribute__((ext_vector_type(4)));
typedef unsigned short ushort4v __attribute__((ext_vector_type(4)));

__device__ __forceinline__ float scrub0(float x){
  unsigned u = __float_as_uint(x);
  return ((u & 0x7F800000u) == 0x7F800000u) ? 0.f : x;
}
__device__ __forceinline__ unsigned short f2bf_rne(float x){
  unsigned u = __float_as_uint(x);
  u += 0x7FFFu + ((u >> 16) & 1u);
  return (unsigned short)(u >> 16);
}
__device__ __forceinline__ float bf2f(unsigned short h){
  return __uint_as_float(((unsigned)h) << 16);
}
// HW RNE pack: 2 f32 -> packed bf16x2 in one VALU op (no gfx950 builtin)
__device__ __forceinline__ unsigned cvtpk(float lo, float hi){
  unsigned r;
  asm("v_cvt_pk_bf16_f32 %0, %1, %2" : "=v"(r) : "v"(lo), "v"(hi));
  return r;
}

__global__ __launch_bounds__(256) void k_zero_int(int* __restrict__ p, int n){
  int i = blockIdx.x*256 + threadIdx.x;
  if (i < n) p[i] = 0;
}

// ---- CSR build over message ids m in [0,2E): target = m<E ? idxL[m] : idxR[m-E]
__global__ __launch_bounds__(256) void k_hist(const int* __restrict__ idxL,
    const int* __restrict__ idxR, int* __restrict__ cnt){
  int m = blockIdx.x*256 + threadIdx.x;
  if (m < N_MSG){
    int t = (m < N_EDGES) ? idxL[m] : idxR[m - N_EDGES];
    atomicAdd(&cnt[t], 1);
  }
}
__global__ __launch_bounds__(256) void k_scan1(const int* __restrict__ cnt,
    int* __restrict__ pos, int* __restrict__ blk_tot){
  const int tid = threadIdx.x;
  const int idx = blockIdx.x*256 + tid;
  int v = (idx < N_VARS) ? cnt[idx] : 0;
  __shared__ int sh[256];
  sh[tid] = v;
  __syncthreads();
#pragma unroll
  for (int o = 1; o < 256; o <<= 1){
    int add = (tid >= o) ? sh[tid - o] : 0;
    __syncthreads();
    sh[tid] += add;
    __syncthreads();
  }
  if (idx < N_VARS) pos[idx] = sh[tid] - v;
  if (tid == 255) blk_tot[blockIdx.x] = sh[255];
}
__global__ __launch_bounds__(256) void k_scan2(const int* __restrict__ blk_tot,
    int* __restrict__ blk_off){
  const int tid = threadIdx.x;
  int v = (tid < NB_STAT) ? blk_tot[tid] : 0;
  __shared__ int sh[256];
  sh[tid] = v;
  __syncthreads();
#pragma unroll
  for (int o = 1; o < 256; o <<= 1){
    int add = (tid >= o) ? sh[tid - o] : 0;
    __syncthreads();
    sh[tid] += add;
    __syncthreads();
  }
  if (tid < NB_STAT) blk_off[tid] = sh[tid] - v;
}
__global__ __launch_bounds__(256) void k_scan3(int* __restrict__ pos,
    const int* __restrict__ blk_off){
  const int idx = blockIdx.x*256 + threadIdx.x;
  if (idx < N_VARS) pos[idx] += blk_off[blockIdx.x];
}
// fill: writes INVERSE permutation morder[slot]=m and nodeof[slot]=target
__global__ __launch_bounds__(256) void k_fill(const int* __restrict__ idxL,
    const int* __restrict__ idxR, int* __restrict__ pos,
    int* __restrict__ morder, int* __restrict__ nodeof){
  int m = blockIdx.x*256 + threadIdx.x;
  if (m < N_MSG){
    int t = (m < N_EDGES) ? idxL[m] : idxR[m - N_EDGES];
    int slot = atomicAdd(&pos[t], 1);
    morder[slot] = m;
    nodeof[slot] = t;
  }
}

// ---- pack W2 + W1 (f32) into B-fragment-ordered bf16 (merged) ----
__global__ __launch_bounds__(256) void k_prep2(const float* __restrict__ W2,
                                               const float* __restrict__ W1,
                                               unsigned short* __restrict__ W2pack,
                                               unsigned short* __restrict__ W1pack){
  if (blockIdx.x < 8){
    int gid = blockIdx.x*256 + threadIdx.x;
    int lane = gid & 63;
    int ks = (gid >> 6) & 3;
    int ntg = gid >> 8;
    int kbase = ks*32 + (lane >> 4)*8;
    int n = ntg*16 + (lane & 15);
#pragma unroll
    for (int j = 0; j < 8; ++j)
      W2pack[gid*8 + j] = f2bf_rne(W2[(kbase + j)*FEAT + n]);
  } else {
    int gid = (blockIdx.x - 8)*256 + threadIdx.x;
    int lane = gid & 63;
    int ks = (gid >> 6) & 3;
    int ntg = gid >> 8;
    int kbase = ks*32 + (lane >> 4)*8;
    int n = ntg*16 + (lane & 15);
#pragma unroll
    for (int j = 0; j < 8; ++j){
      int k = kbase + j;
      float v = (n < 128) ? W1[k*FEAT + n] : W1[(128 + k)*FEAT + (n - 128)];
      W1pack[gid*8 + j] = f2bf_rne(v);
    }
  }
}

// ---- PQ = x @ [W1top | W1bot] via MFMA bf16 -> bf16 store.
// Q-half accumulators init with b1 (bias folded into PQb).
// Also zeroes red (block 0) and the whole recagg buffer (all blocks).
#define X_STRIDE 136
__global__ __launch_bounds__(256) void k_pq(const float* __restrict__ xf,
                                            const unsigned short* __restrict__ xb,
                                            int src_f32,
                                            const unsigned short* __restrict__ W1pack,
                                            const float* __restrict__ b1v,
                                            unsigned short* __restrict__ PQb,
                                            float* __restrict__ red,
                                            float4* __restrict__ recz){
  __shared__ __align__(16) unsigned short Xbf[32*X_STRIDE];
  const int tid = threadIdx.x;
  const int row0 = blockIdx.x * 32;
  if (blockIdx.x == 0) red[tid] = 0.f;
  {  // zero recagg: 1250 blocks * 256 threads * 4 float4 = 1,280,000 float4
    const int zid = blockIdx.x*256 + tid;
#pragma unroll
    for (int i = 0; i < 4; ++i)
      recz[zid + i*320000] = make_float4(0.f,0.f,0.f,0.f);
  }
  if (src_f32){
    const int c4 = (tid & 31)*4, g8 = tid >> 5;
#pragma unroll
    for (int r = 0; r < 4; ++r){
      int row = g8*4 + r;
      const float4 v = *(const float4*)&xf[(row0 + row)*FEAT + c4];
      uint2 uu;
      uu.x = cvtpk(v.x, v.y);
      uu.y = cvtpk(v.z, v.w);
      *(uint2*)&Xbf[row*X_STRIDE + c4] = uu;
    }
  } else {
    const int c8 = (tid & 15)*8, g16 = tid >> 4;
#pragma unroll
    for (int r = 0; r < 2; ++r){
      int row = r*16 + g16;
      *(short8*)&Xbf[row*X_STRIDE + c8] = *(const short8*)&xb[(row0 + row)*FEAT + c8];
    }
  }
  __syncthreads();
  const int w = tid >> 6, lane = tid & 63;
  const int quad = lane >> 4, mcol = lane & 15;
  float bi0 = 0.f, bi1 = 0.f, bi2 = 0.f, bi3 = 0.f;
  if (w >= 2){
    int nb = (w - 2)*64 + mcol;
    bi0 = b1v[nb]; bi1 = b1v[nb + 16]; bi2 = b1v[nb + 32]; bi3 = b1v[nb + 48];
  }
#pragma unroll
  for (int mt = 0; mt < 2; ++mt){
    floatx4 a0 = {bi0,bi0,bi0,bi0};
    floatx4 a1 = {bi1,bi1,bi1,bi1};
    floatx4 a2 = {bi2,bi2,bi2,bi2};
    floatx4 a3 = {bi3,bi3,bi3,bi3};
#pragma unroll
    for (int ks = 0; ks < 4; ++ks){
      short8 a = *(const short8*)&Xbf[(mt*16 + mcol)*X_STRIDE + ks*32 + quad*8];
      const unsigned short* bp = W1pack + ((w*16 + ks)*64 + lane)*8;
      short8 b0 = *(const short8*)(bp);
      short8 b1 = *(const short8*)(bp + 2048);
      short8 b2 = *(const short8*)(bp + 4096);
      short8 b3 = *(const short8*)(bp + 6144);
      a0 = __builtin_amdgcn_mfma_f32_16x16x32_bf16(a, b0, a0, 0, 0, 0);
      a1 = __builtin_amdgcn_mfma_f32_16x16x32_bf16(a, b1, a1, 0, 0, 0);
      a2 = __builtin_amdgcn_mfma_f32_16x16x32_bf16(a, b2, a2, 0, 0, 0);
      a3 = __builtin_amdgcn_mfma_f32_16x16x32_bf16(a, b3, a3, 0, 0, 0);
    }
#pragma unroll
    for (int reg = 0; reg < 4; ++reg){
      unsigned u01 = cvtpk(a0[reg], a1[reg]);
      unsigned u23 = cvtpk(a2[reg], a3[reg]);
      size_t base = (size_t)(row0 + mt*16 + quad*4 + reg)*(2*FEAT) + w*64 + mcol;
      PQb[base]      = (unsigned short)u01;
      PQb[base + 16] = (unsigned short)(u01 >> 16);
      PQb[base + 32] = (unsigned short)u23;
      PQb[base + 48] = (unsigned short)(u23 >> 16);
    }
  }
}

#define U_STRIDE 136   // bf16 elems (phase A/B row-major layout)
#define ZT_STRIDE 68   // bf16 elems (phase C col-major layout, aliased)

// ---- FUSED: message MLP + LayerNorm + CSR-ordered aggregation ----
// Phase A: gather P[b]+Q'[a] (b1 pre-folded), relu -> Ubf (LDS bf16, cvt_pk)
// Phase B: MFMA with W2 (b2 in acc init), relu, per-row LayerNorm
// Phase B': write bf16 Z TRANSPOSED into the same LDS tile (col-major), packed
//           along the reg dimension (4 consecutive rows) -> 8 ds_write_b64
// Phase C: all 256 threads; col=tid&127, half=tid>>7 walks 32 rows (8 b64
//          ds_reads); run-break mask precomputed by wave 0 ballot and hoisted
//          to SGPR -> break test is scalar; runs emitted *1/deg; boundary
//          runs atomicAdd, interior runs plain store.
__global__ __launch_bounds__(256) void k_msgagg(const unsigned short* __restrict__ PQb,
    const unsigned short* __restrict__ W2pack,
    const float* __restrict__ b2v, const float* __restrict__ ln_g, const float* __restrict__ ln_b,
    const int* __restrict__ idxL, const int* __restrict__ idxR,
    const int* __restrict__ morder, const int* __restrict__ nodeof,
    const float* __restrict__ degrees,
    float* __restrict__ rec){
  __shared__ __align__(16) unsigned short Ubf[64*U_STRIDE];   // aliased U then Z^T
  __shared__ int sTa[64], sTb[64];
  __shared__ float sDinv[64];
  __shared__ int sEdge[2];
  __shared__ unsigned sBrkLo, sBrkHi;
  const int tid = threadIdx.x;
  const int s0 = blockIdx.x * 64;
  if (tid < 64){
    int m = morder[s0 + tid];
    int e = (m < N_EDGES) ? m : (m - N_EDGES);
    int l = idxL[e], r = idxR[e];
    int ta = (m < N_EDGES) ? l : r;
    sTa[tid] = ta;
    sTb[tid] = (m < N_EDGES) ? r : l;
    sDinv[tid] = 1.f / degrees[ta];
  } else if (tid == 64){
    sEdge[0] = (s0 == 0) ? -1 : nodeof[s0 - 1];
  } else if (tid == 65){
    sEdge[1] = (s0 + 64 >= N_MSG) ? -1 : nodeof[s0 + 64];
  }
  __syncthreads();
  if (tid < 64){
    bool d = (tid == 63) ? true : (sTa[tid + 1] != sTa[tid]);
    unsigned long long b = __ballot(d ? 1 : 0);
    if (tid == 0){ sBrkLo = (unsigned)b; sBrkHi = (unsigned)(b >> 32); }
  }
  {
    const int c8 = (tid & 15)*8, g16 = tid >> 4;
    short8 pb[4], qb[4];
#pragma unroll
    for (int r = 0; r < 4; ++r){
      int row = r*16 + g16;
      pb[r] = *(const short8*)&PQb[sTb[row]*(2*FEAT) + c8];
      qb[r] = *(const short8*)&PQb[sTa[row]*(2*FEAT) + FEAT + c8];
    }
#pragma unroll
    for (int r = 0; r < 4; ++r){
      int row = r*16 + g16;
      float f[8];
#pragma unroll
      for (int j = 0; j < 8; ++j)
        f[j] = fmaxf(bf2f((unsigned short)pb[r][j]) + bf2f((unsigned short)qb[r][j]), 0.f);
      uint4 uu;
      uu.x = cvtpk(f[0], f[1]);
      uu.y = cvtpk(f[2], f[3]);
      uu.z = cvtpk(f[4], f[5]);
      uu.w = cvtpk(f[6], f[7]);
      *(uint4*)&Ubf[row*U_STRIDE + c8] = uu;
    }
  }
  __syncthreads();
  const int w = tid >> 6, lane = tid & 63;
  const int quad = lane >> 4, mcol = lane & 15;
  const int rbase = w*16;
  floatx4 acc[8];
#pragma unroll
  for (int nt = 0; nt < 8; ++nt){
    float b = b2v[nt*16 + mcol];
    acc[nt] = (floatx4){b, b, b, b};
  }
#pragma unroll
  for (int ks = 0; ks < 4; ++ks){
    short8 a = *(const short8*)&Ubf[(rbase + mcol)*U_STRIDE + ks*32 + quad*8];
#pragma unroll
    for (int nt = 0; nt < 8; ++nt){
      short8 b = *(const short8*)(W2pack + ((nt*4 + ks)*64 + lane)*8);
      acc[nt] = __builtin_amdgcn_mfma_f32_16x16x32_bf16(a, b, acc[nt], 0, 0, 0);
    }
  }
  float z[8][4];
#pragma unroll
  for (int nt = 0; nt < 8; ++nt){
#pragma unroll
    for (int reg = 0; reg < 4; ++reg) z[nt][reg] = fmaxf(acc[nt][reg], 0.f);
  }
  float ps[4], pq[4];
#pragma unroll
  for (int reg = 0; reg < 4; ++reg){
    ps[reg] = 0.f; pq[reg] = 0.f;
#pragma unroll
    for (int nt = 0; nt < 8; ++nt){
      ps[reg] += z[nt][reg];
      pq[reg] += z[nt][reg]*z[nt][reg];
    }
  }
#pragma unroll
  for (int o = 1; o < 16; o <<= 1){
#pragma unroll
    for (int reg = 0; reg < 4; ++reg){
      ps[reg] += __shfl_xor(ps[reg], o);
      pq[reg] += __shfl_xor(pq[reg], o);
    }
  }
  float lgv[8], lbv[8];
#pragma unroll
  for (int nt = 0; nt < 8; ++nt){
    lgv[nt] = ln_g[nt*16 + mcol];
    lbv[nt] = ln_b[nt*16 + mcol];
  }
  float muv[4], rvv[4];
#pragma unroll
  for (int reg = 0; reg < 4; ++reg){
    float mu = ps[reg] * (1.f/FEAT);
    float var = fmaxf(pq[reg] * (1.f/FEAT) - mu*mu, 0.f);
    muv[reg] = mu;
    rvv[reg] = rsqrtf(var + EPSF);
  }
  // LN outputs packed along reg (consecutive rows of a column)
  unsigned w0p[8], w1p[8];
#pragma unroll
  for (int nt = 0; nt < 8; ++nt){
    float o0 = scrub0(lgv[nt]*(z[nt][0] - muv[0])*rvv[0] + lbv[nt]);
    float o1 = scrub0(lgv[nt]*(z[nt][1] - muv[1])*rvv[1] + lbv[nt]);
    float o2 = scrub0(lgv[nt]*(z[nt][2] - muv[2])*rvv[2] + lbv[nt]);
    float o3 = scrub0(lgv[nt]*(z[nt][3] - muv[3])*rvv[3] + lbv[nt]);
    w0p[nt] = cvtpk(o0, o1);
    w1p[nt] = cvtpk(o2, o3);
  }
  __syncthreads();   // all waves done reading Ubf -> safe to overwrite (as Z^T)
#pragma unroll
  for (int nt = 0; nt < 8; ++nt){
    uint2 u; u.x = w0p[nt]; u.y = w1p[nt];
    *(uint2*)&Ubf[(nt*16 + mcol)*ZT_STRIDE + rbase + quad*4] = u;
  }
  __syncthreads();
  // Phase C: segmented sum over sorted rows; 2 halves x 128 cols
  {
    const int col = tid & 127, h = tid >> 7;
    const int rbeg = h*32;
    const unsigned bm = __builtin_amdgcn_readfirstlane(h ? sBrkHi : sBrkLo);
    ushort4v rv4[8];
#pragma unroll
    for (int k = 0; k < 8; ++k)
      rv4[k] = *(const ushort4v*)&Ubf[col*ZT_STRIDE + rbeg + k*4];
    float accv = 0.f;
    int cur = sTa[rbeg];
    bool part = (rbeg == 0) ? (sEdge[0] == cur) : (sTa[rbeg-1] == cur);
#pragma unroll
    for (int i = 0; i < 32; ++i){
      accv += bf2f((unsigned short)rv4[i >> 2][i & 3]);
      const bool realbrk = (bm >> i) & 1u;
      if ((i == 31) | realbrk){
        const int r = rbeg + i;
        bool cont = (i == 31) && ((r == 63) ? (sEdge[1] == cur) : !realbrk);
        float v = accv * sDinv[r];
        float* dst = &rec[(size_t)cur*FEAT + col];
        if (part | cont) atomicAdd(dst, v);
        else *dst = v;
        accv = 0.f;
        part = false;
        if (i < 31) cur = sTa[r + 1];
      }
    }
  }
}

// ================= fallback path (no CSR) =================
__global__ __launch_bounds__(256) void k_edge(const unsigned short* __restrict__ PQb,
    const unsigned short* __restrict__ W2pack,
    const float* __restrict__ b2v, const float* __restrict__ ln_g, const float* __restrict__ ln_b,
    const int* __restrict__ idxL, const int* __restrict__ idxR,
    float* __restrict__ agg){
  __shared__ __align__(16) unsigned short Ubf[32*U_STRIDE];
  __shared__ float sS[64], sQ[64];
  __shared__ int sTa[32], sTb[32];
  const int tid = threadIdx.x;
  const int m0 = blockIdx.x * 32;
  if (tid < 32){
    int m = m0 + tid;
    int e = (m < N_EDGES) ? m : (m - N_EDGES);
    int l = idxL[e], r = idxR[e];
    sTa[tid] = (m < N_EDGES) ? l : r;
    sTb[tid] = (m < N_EDGES) ? r : l;
  }
  __syncthreads();
  {
    const int c8 = (tid & 15)*8, g16 = tid >> 4;
#pragma unroll
    for (int r = 0; r < 2; ++r){
      int row = r*16 + g16;
      short8 pb = *(const short8*)&PQb[sTb[row]*(2*FEAT) + c8];
      short8 qb = *(const short8*)&PQb[sTa[row]*(2*FEAT) + FEAT + c8];
      float f[8];
#pragma unroll
      for (int j = 0; j < 8; ++j)
        f[j] = fmaxf(bf2f((unsigned short)pb[j]) + bf2f((unsigned short)qb[j]), 0.f);
      uint4 uu;
      uu.x = cvtpk(f[0], f[1]);
      uu.y = cvtpk(f[2], f[3]);
      uu.z = cvtpk(f[4], f[5]);
      uu.w = cvtpk(f[6], f[7]);
      *(uint4*)&Ubf[row*U_STRIDE + c8] = uu;
    }
  }
  __syncthreads();
  const int w = tid >> 6, lane = tid & 63;
  const int mt = w & 1, nhalf = w >> 1;
  const int quad = lane >> 4, mcol = lane & 15;
  float bb0 = b2v[nhalf*64 + 0*16 + mcol];
  float bb1 = b2v[nhalf*64 + 1*16 + mcol];
  float bb2 = b2v[nhalf*64 + 2*16 + mcol];
  float bb3 = b2v[nhalf*64 + 3*16 + mcol];
  floatx4 acc0 = {bb0,bb0,bb0,bb0};
  floatx4 acc1 = {bb1,bb1,bb1,bb1};
  floatx4 acc2 = {bb2,bb2,bb2,bb2};
  floatx4 acc3 = {bb3,bb3,bb3,bb3};
#pragma unroll
  for (int ks = 0; ks < 4; ++ks){
    short8 a = *(const short8*)&Ubf[(mt*16 + mcol)*U_STRIDE + ks*32 + quad*8];
    const unsigned short* bp = W2pack + ((nhalf*4*256) + ks*64 + lane)*8;
    short8 bq0 = *(const short8*)(bp);
    short8 bq1 = *(const short8*)(bp + 2048);
    short8 bq2 = *(const short8*)(bp + 4096);
    short8 bq3 = *(const short8*)(bp + 6144);
    acc0 = __builtin_amdgcn_mfma_f32_16x16x32_bf16(a, bq0, acc0, 0, 0, 0);
    acc1 = __builtin_amdgcn_mfma_f32_16x16x32_bf16(a, bq1, acc1, 0, 0, 0);
    acc2 = __builtin_amdgcn_mfma_f32_16x16x32_bf16(a, bq2, acc2, 0, 0, 0);
    acc3 = __builtin_amdgcn_mfma_f32_16x16x32_bf16(a, bq3, acc3, 0, 0, 0);
  }
  float z[4][4];
#pragma unroll
  for (int nt = 0; nt < 4; ++nt){
    floatx4 a4 = (nt == 0) ? acc0 : (nt == 1) ? acc1 : (nt == 2) ? acc2 : acc3;
#pragma unroll
    for (int reg = 0; reg < 4; ++reg) z[nt][reg] = fmaxf(a4[reg], 0.f);
  }
  float ps[4], pq[4];
#pragma unroll
  for (int reg = 0; reg < 4; ++reg){
    ps[reg] = z[0][reg] + z[1][reg] + z[2][reg] + z[3][reg];
    pq[reg] = z[0][reg]*z[0][reg] + z[1][reg]*z[1][reg] + z[2][reg]*z[2][reg] + z[3][reg]*z[3][reg];
  }
#pragma unroll
  for (int o = 1; o < 16; o <<= 1){
#pragma unroll
    for (int reg = 0; reg < 4; ++reg){
      ps[reg] += __shfl_xor(ps[reg], o);
      pq[reg] += __shfl_xor(pq[reg], o);
    }
  }
  if (mcol == 0){
#pragma unroll
    for (int reg = 0; reg < 4; ++reg){
      int row = mt*16 + quad*4 + reg;
      sS[nhalf*32 + row] = ps[reg];
      sQ[nhalf*32 + row] = pq[reg];
    }
  }
  __syncthreads();
  int colv[4]; float lgv[4], lbv[4];
#pragma unroll
  for (int nt = 0; nt < 4; ++nt){
    colv[nt] = nhalf*64 + nt*16 + mcol;
    lgv[nt] = ln_g[colv[nt]];
    lbv[nt] = ln_b[colv[nt]];
  }
#pragma unroll
  for (int reg = 0; reg < 4; ++reg){
    int row = mt*16 + quad*4 + reg;
    float s = sS[row] + sS[32 + row];
    float q = sQ[row] + sQ[32 + row];
    float mu = s * (1.f/FEAT);
    float var = fmaxf(q * (1.f/FEAT) - mu*mu, 0.f);
    float rv = rsqrtf(var + EPSF);
    int a = sTa[row];
#pragma unroll
    for (int nt = 0; nt < 4; ++nt){
      float o = scrub0(lgv[nt]*(z[nt][reg] - mu)*rv + lbv[nt]);
      atomicAdd(&agg[a*FEAT + colv[nt]], o);
    }
  }
}

__global__ __launch_bounds__(256) void k_stats(const float* __restrict__ src,
    const float* __restrict__ degrees, int divide, float* __restrict__ red){
  const int tid = threadIdx.x;
  const int j = tid & 127, half_sel = tid >> 7;
  const int n0 = blockIdx.x * 64;
  float s1 = 0.f, s2 = 0.f;
  for (int i = half_sel; i < 64; i += 2){
    int n = n0 + i;
    float v = src[n*FEAT + j];
    if (divide) v /= degrees[n];
    s1 += v;
    s2 += v*v;
  }
  __shared__ float sh1[256], sh2[256];
  sh1[tid] = s1; sh2[tid] = s2;
  __syncthreads();
  if (half_sel == 0){
    atomicAdd(&red[j],       sh1[tid] + sh1[tid+128]);
    atomicAdd(&red[128 + j], sh2[tid] + sh2[tid+128]);
  }
}

// ---- BN apply + logits + softmax + argmax; bf16 state out ----
__global__ __launch_bounds__(256) void k_bn(const float* __restrict__ src,
    const float* __restrict__ degrees, int divide, const float* __restrict__ red,
    const float* __restrict__ bn_g, const float* __restrict__ bn_b,
    const float* __restrict__ Wd, const float* __restrict__ bd,
    unsigned short* __restrict__ state_bf, int* __restrict__ asg,
    float* __restrict__ out_phi, float* __restrict__ out_asg, int t){
  const int w = threadIdx.x >> 6, l = threadIdx.x & 63;
  const int n = blockIdx.x*4 + w;
  const float invN = 1.f / (float)N_VARS;
  float mu0 = red[l]*invN,     mu1 = red[l+64]*invN;
  float v0  = fmaxf(red[128+l]*invN    - mu0*mu0, 0.f);
  float v1  = fmaxf(red[128+l+64]*invN - mu1*mu1, 0.f);
  float rv0 = rsqrtf(v0 + EPSF);
  float rv1 = rsqrtf(v1 + EPSF);
  float dinv = divide ? (1.f / degrees[n]) : 1.f;
  float r0 = src[n*FEAT + l]    * dinv;
  float r1 = src[n*FEAT + l+64] * dinv;
  float s0 = scrub0(bn_g[l]   *(r0 - mu0)*rv0 + bn_b[l]);
  float s1 = scrub0(bn_g[l+64]*(r1 - mu1)*rv1 + bn_b[l+64]);
  state_bf[n*FEAT + l]    = f2bf_rne(s0);
  state_bf[n*FEAT + l+64] = f2bf_rne(s1);
  float p[4];
#pragma unroll
  for (int d = 0; d < 4; ++d)
    p[d] = s0*Wd[l*4 + d] + s1*Wd[(l+64)*4 + d];
#pragma unroll
  for (int o = 32; o > 0; o >>= 1){
#pragma unroll
    for (int d = 0; d < 4; ++d) p[d] += __shfl_xor(p[d], o);
  }
  if (l == 0){
    float lg[4];
#pragma unroll
    for (int d = 0; d < 4; ++d) lg[d] = scrub0(p[d] + bd[d]);
    float mx = fmaxf(fmaxf(lg[0],lg[1]), fmaxf(lg[2],lg[3]));
    float ex[4]; float ssum = 0.f;
#pragma unroll
    for (int d = 0; d < 4; ++d){ ex[d] = expf(lg[d] - mx); ssum += ex[d]; }
    float inv = 1.f / ssum;
    int am = 0; float bv = -1.f;
#pragma unroll
    for (int d = 0; d < 4; ++d){
      float pv = scrub0(ex[d]*inv);
      out_phi[n*12 + t*4 + d] = pv;
      if (pv > bv){ bv = pv; am = d; }
    }
    asg[n*3 + t] = am;
    if (t == 2) out_asg[n] = (float)am;
  }
}

// ---- merged pair-losses (1 thread/edge, 3 t's) + edge-conflicts ----
__global__ __launch_bounds__(256) void k_lossconf(const float* __restrict__ phi,
    const int* __restrict__ iL, const int* __restrict__ iR,
    const int* __restrict__ iLp, const int* __restrict__ iRp,
    const float* __restrict__ rel, const float* __restrict__ conf,
    const int* __restrict__ asg, float* __restrict__ out_ec,
    float* __restrict__ part_l1, float* __restrict__ part_l2,
    float* __restrict__ part_conf){
  if (blockIdx.x < NB_PAIR){
    const int e = blockIdx.x*256 + threadIdx.x;
    float p1 = 0.f, p2 = 0.f;
    if (e < N_EDGES + N_CONFP){
      const int isrel = (e < N_EDGES);
      const int l = isrel ? iL[e] : iLp[e - N_EDGES];
      const int r = isrel ? iR[e] : iRp[e - N_EDGES];
      const float* M = isrel ? rel : conf;
      const float2* plp = (const float2*)(phi + (size_t)l*12);
      const float2* prp = (const float2*)(phi + (size_t)r*12);
      float L[12], R[12];
#pragma unroll
      for (int k = 0; k < 6; ++k){
        float2 a = plp[k], b = prp[k];
        L[2*k] = a.x; L[2*k+1] = a.y;
        R[2*k] = b.x; R[2*k+1] = b.y;
      }
      float acc = 0.f;
#pragma unroll
      for (int tt = 0; tt < 3; ++tt){
        const float* a = L + tt*4;
        const float* b = R + tt*4;
        float s = 0.f;
#pragma unroll
        for (int j = 0; j < 4; ++j){
          float tj = a[0]*M[0*4+j] + a[1]*M[1*4+j] + a[2]*M[2*4+j] + a[3]*M[3*4+j];
          s += tj*b[j];
        }
        s = scrub0(s); s = fmaxf(s, 1e-35f);
        acc -= __logf(s);
      }
      if (isrel) p1 = acc; else p2 = acc;
    }
    __shared__ float sh1[256], sh2[256];
    sh1[threadIdx.x] = p1; sh2[threadIdx.x] = p2;
    __syncthreads();
    for (int k = 128; k > 0; k >>= 1){
      if (threadIdx.x < k){
        sh1[threadIdx.x] += sh1[threadIdx.x + k];
        sh2[threadIdx.x] += sh2[threadIdx.x + k];
      }
      __syncthreads();
    }
    if (threadIdx.x == 0){
      part_l1[blockIdx.x] = sh1[0];
      part_l2[blockIdx.x] = sh2[0];
    }
  } else {
    const int bid = blockIdx.x - NB_PAIR;
    const int e = bid*256 + threadIdx.x;
    float c2 = 0.f;
    if (e < N_EDGES){
      int l = iL[e], r = iR[e];
#pragma unroll
      for (int tt = 0; tt < 3; ++tt){
        int ai = asg[l*3+tt] & 3, bi = asg[r*3+tt] & 3;
        float c = scrub0(1.f - rel[ai*4 + bi]);
        out_ec[e*3 + tt] = c;
        if (tt == 2) c2 = c;
      }
    }
    __shared__ float sh[256];
    sh[threadIdx.x] = c2;
    __syncthreads();
    for (int k = 128; k > 0; k >>= 1){
      if (threadIdx.x < k) sh[threadIdx.x] += sh[threadIdx.x + k];
      __syncthreads();
    }
    if (threadIdx.x == 0) part_conf[bid] = sh[0];
  }
}

// ---- final scalar reduce -> out[0], out[1], out[NCONF_SLOT] ----
__global__ __launch_bounds__(256) void k_fin(const float* __restrict__ part_conf,
    const float* __restrict__ part_l1, const float* __restrict__ part_l2,
    float* __restrict__ out){
  const int tid = threadIdx.x;
  float a = 0.f, ca = 0.f, b = 0.f, cb = 0.f, c = 0.f;
  for (int i = tid; i < NB_PAIR; i += 256){
    float y = part_l1[i] - ca; float t = a + y; ca = (t - a) - y; a = t;
    float y2 = part_l2[i] - cb; float t2 = b + y2; cb = (t2 - b) - y2; b = t2;
  }
  for (int i = tid; i < NB_CONF; i += 256) c += part_conf[i];
  __shared__ float sh1[256], sh2[256], sh3[256];
  sh1[tid] = a; sh2[tid] = b; sh3[tid] = c;
  __syncthreads();
  for (int k = 128; k > 0; k >>= 1){
    if (tid < k){
      sh1[tid] += sh1[tid + k];
      sh2[tid] += sh2[tid + k];
      sh3[tid] += sh3[tid + k];
    }
    __syncthreads();
  }
  if (tid == 0){
    out[0] = sh1[0]/(float)N_EDGES + sh2[0]/(10.f*(float)N_CONFP);
    float nc = sh3[0];
    out[NCONF_SLOT] = nc;
    out[1] = nc / (float)N_EDGES;
  }
}

extern "C" void kernel_launch(void* const* d_in, const int* in_sizes, int n_in,
                              void* d_out, int out_size, void* d_ws, size_t ws_size,
                              hipStream_t stream){
  const float* state0  = (const float*)d_in[0];
  const float* W1      = (const float*)d_in[1];
  const float* b1v     = (const float*)d_in[2];
  const float* W2      = (const float*)d_in[3];
  const float* b2v     = (const float*)d_in[4];
  const float* ln_g    = (const float*)d_in[5];
  const float* ln_b    = (const float*)d_in[6];
  const float* bn_g    = (const float*)d_in[7];
  const float* bn_b    = (const float*)d_in[8];
  const float* Wd      = (const float*)d_in[9];
  const float* bd      = (const float*)d_in[10];
  const float* rel     = (const float*)d_in[11];
  const float* confm   = (const float*)d_in[12];
  const float* degrees = (const float*)d_in[13];
  const int* idxL = (const int*)d_in[14];
  const int* idxR = (const int*)d_in[15];
  const int* iLp  = (const int*)d_in[16];
  const int* iRp  = (const int*)d_in[17];

  char* ws = (char*)d_ws;
  unsigned short* state_bf = (unsigned short*)(ws);          // 10,240,000
  unsigned short* PQb  = (unsigned short*)(ws + 10240000);   // 20,480,000
  float*  recagg    = (float*)(ws + 30720000);               // 20,480,000
  int*    asg       = (int*)  (ws + 51200000);               //    480,000
  float*  red       = (float*)(ws + 51840768);               //      1,024
  float*  part_l1   = (float*)(ws + 51841792);               //     14,068
  float*  part_l2   = (float*)(ws + 51855860);               //     14,068
  float*  part_conf = (float*)(ws + 51869928);               //      3,128
  unsigned short* W2pack = (unsigned short*)(ws + 51873056); //     32,768
  unsigned short* W1pack = (unsigned short*)(ws + 51905824); //     65,536
  int*    pos       = (int*)(ws + 51971360);                 //    160,000
  int*    cnt       = (int*)(ws + 52131360);                 //    160,000
  int*    morder    = (int*)(ws + 52291360);                 //  1,600,000
  int*    blk_tot   = (int*)(ws + 53891360);                 //      1,024
  int*    blk_off   = (int*)(ws + 53892384);                 //      1,024
  int*    nodeof    = (int*)(ws + 53893408);                 //  1,600,000
  const int use_csr = (ws_size >= (size_t)55493408) ? 1 : 0;

  float* out     = (float*)d_out;
  float* out_phi = out + 2;
  float* out_ec  = out + 480002;
  float* out_asg = out + 1080002;

  k_prep2<<<24, 256, 0, stream>>>(W2, W1, W2pack, W1pack);

  if (use_csr){
    k_zero_int<<<NB_STAT, 256, 0, stream>>>(cnt, N_VARS);
    k_hist<<<(N_MSG + 255)/256, 256, 0, stream>>>(idxL, idxR, cnt);
    k_scan1<<<NB_STAT, 256, 0, stream>>>(cnt, pos, blk_tot);
    k_scan2<<<1, 256, 0, stream>>>(blk_tot, blk_off);
    k_scan3<<<NB_STAT, 256, 0, stream>>>(pos, blk_off);
    k_fill<<<(N_MSG + 255)/256, 256, 0, stream>>>(idxL, idxR, pos, morder, nodeof);
  }

  for (int t = 0; t < T_ITERS; ++t){
    k_pq<<<N_VARS/32, 256, 0, stream>>>(state0, state_bf, (t == 0) ? 1 : 0, W1pack, b1v,
                                        PQb, red, (float4*)recagg);
    if (use_csr){
      k_msgagg<<<N_MSG/64, 256, 0, stream>>>(PQb, W2pack, b2v, ln_g, ln_b,
                                             idxL, idxR, morder, nodeof, degrees, recagg);
      k_stats<<<NB_STAT2, 256, 0, stream>>>(recagg, degrees, 0, red);
      k_bn<<<N_VARS/4, 256, 0, stream>>>(recagg, degrees, 0, red, bn_g, bn_b, Wd, bd,
                                         state_bf, asg, out_phi, out_asg, t);
    } else {
      k_edge<<<N_MSG/32, 256, 0, stream>>>(PQb, W2pack, b2v, ln_g, ln_b, idxL, idxR, recagg);
      k_stats<<<NB_STAT2, 256, 0, stream>>>(recagg, degrees, 1, red);
      k_bn<<<N_VARS/4, 256, 0, stream>>>(recagg, degrees, 1, red, bn_g, bn_b, Wd, bd,
                                         state_bf, asg, out_phi, out_asg, t);
    }
  }
  k_lossconf<<<NB_PAIR + NB_CONF, 256, 0, stream>>>(out_phi, idxL, idxR, iLp, iRp, rel, confm,
                                                    asg, out_ec, part_l1, part_l2, part_conf);
  k_fin<<<1, 256, 0, stream>>>(part_conf, part_l1, part_l2, out);
}